// Round 7
// baseline (460.548 us; speedup 1.0000x reference)
//
#include <hip/hip_runtime.h>
#include <hip/hip_bf16.h>
#include <math.h>

#define DM 768
#define NH 12
#define DH 64
#define DMLP 3072
#define BATCH 8
#define SEQ 1024
#define NTOK (BATCH*SEQ)
#define QKVN (3*DM)
#define LN_EPS 1e-5f

typedef __hip_bfloat16 bf16;
typedef __attribute__((ext_vector_type(8))) short bf16x8;
typedef __attribute__((ext_vector_type(4))) float f32x4;

#define MFMA16(a,b,c) __builtin_amdgcn_mfma_f32_16x16x32_bf16((a),(b),(c),0,0,0)

__device__ __forceinline__ float us2f(unsigned short u){
    unsigned int i = ((unsigned int)u) << 16; float f; __builtin_memcpy(&f, &i, 4); return f;
}
__device__ __forceinline__ short f2bs(float f){
    bf16 h = __float2bfloat16(f); short s; __builtin_memcpy(&s, &h, 2); return s;
}
__device__ __forceinline__ float tof(float x){ return x; }
__device__ __forceinline__ float tof(short x){ return us2f((unsigned short)x); }

// gelu_new(x) = x * sigmoid(2c(x + 0.044715 x^3)), c = sqrt(2/pi). ~7 VALU ops.
__device__ __forceinline__ float gelu_f(float x){
    float y = 1.5957691216057308f*(x + 0.044715f*x*x*x);
    return x * __builtin_amdgcn_rcpf(1.0f + __expf(-y));
}

// async 16B global->LDS. LDS dest = wave-uniform base + lane*16 (fixed linear).
__device__ __forceinline__ void gload16(const void* g, void* l){
    __builtin_amdgcn_global_load_lds(
        (const __attribute__((address_space(1))) void*)g,
        (__attribute__((address_space(3))) void*)l, 16, 0, 0);
}

// ---------------- transpose + fp32->bf16 convert: out[N][K] = in[K][N] ----------------
__global__ __launch_bounds__(256) void transpose_cvt(const float* __restrict__ in,
                                                     short* __restrict__ out,
                                                     int K, int N)
{
    __shared__ float t[32][33];
    int n0 = blockIdx.x*32, k0 = blockIdx.y*32;
    int tx = threadIdx.x & 31, ty = threadIdx.x >> 5;
    #pragma unroll
    for (int i = 0; i < 32; i += 8)
        t[ty+i][tx] = in[(size_t)(k0+ty+i)*N + n0+tx];
    __syncthreads();
    #pragma unroll
    for (int i = 0; i < 32; i += 8)
        out[(size_t)(n0+ty+i)*K + k0+tx] = f2bs(t[tx][ty+i]);
}

// qkv weights: W_{q,k,v}[h][k][e] -> wqkvT[n = which*768 + h*64 + e][k], bf16
__global__ __launch_bounds__(256) void transpose_cvt_qkv(const float* __restrict__ Wq,
                                                         const float* __restrict__ Wk,
                                                         const float* __restrict__ Wv,
                                                         short* __restrict__ out)
{
    __shared__ float t[32][33];
    int zz = blockIdx.z;
    int which = zz / 12, h = zz % 12;
    const float* in = (which == 0 ? Wq : which == 1 ? Wk : Wv) + (size_t)h*DM*DH;
    short* o = out + ((size_t)which*DM + h*DH)*DM;
    int n0 = blockIdx.x*32, k0 = blockIdx.y*32;
    int tx = threadIdx.x & 31, ty = threadIdx.x >> 5;
    #pragma unroll
    for (int i = 0; i < 32; i += 8)
        t[ty+i][tx] = in[(size_t)(k0+ty+i)*DH + n0+tx];
    __syncthreads();
    #pragma unroll
    for (int i = 0; i < 32; i += 8)
        o[(size_t)(n0+ty+i)*DM + k0+tx] = f2bs(t[tx][ty+i]);
}

// concat b_Q|b_K|b_V -> [2304] fp32
__global__ __launch_bounds__(256) void prep_qkv_bias(const float* bQ, const float* bK, const float* bV,
                                                     float* __restrict__ out)
{
    int idx = blockIdx.x*256 + threadIdx.x;
    if (idx >= QKVN) return;
    int which = idx / DM, hc = idx % DM;
    const float* b = (which == 0) ? bQ : ((which == 1) ? bK : bV);
    out[idx] = b[hc];
}

// v_rm [8192][768] bf16 -> vT [(b*12+h)*64 + d][1024] bf16
__global__ __launch_bounds__(256) void transpose_v(const short* __restrict__ v_rm,
                                                   short* __restrict__ vT)
{
    __shared__ short t[64][65];
    int st = blockIdx.x, h = blockIdx.y, b = blockIdx.z;
    int tok = threadIdx.x >> 2, seg = (threadIdx.x & 3)*16;
    const short* src = v_rm + (size_t)(b*SEQ + st*64 + tok)*DM + h*DH + seg;
    bf16x8 a0 = *(const bf16x8*)src;
    bf16x8 a1 = *(const bf16x8*)(src + 8);
    #pragma unroll
    for (int i = 0; i < 8; i++) t[seg + i][tok]     = a0[i];
    #pragma unroll
    for (int i = 0; i < 8; i++) t[seg + 8 + i][tok] = a1[i];
    __syncthreads();
    int d = threadIdx.x >> 2; int sk = (threadIdx.x & 3)*16;
    short* dst = vT + ((size_t)(b*NH + h)*DH + d)*SEQ + st*64 + sk;
    bf16x8 w0, w1;
    #pragma unroll
    for (int i = 0; i < 8; i++) w0[i] = t[d][sk + i];
    #pragma unroll
    for (int i = 0; i < 8; i++) w1[i] = t[d][sk + 8 + i];
    *(bf16x8*)dst = w0;
    *(bf16x8*)(dst + 8) = w1;
}

// ---------------- layernorm ----------------
__device__ __forceinline__ float block_reduce_sum(float v, float* buf){
    int tid = threadIdx.x;
    buf[tid] = v; __syncthreads();
    for (int s = 128; s > 0; s >>= 1){
        if (tid < s) buf[tid] += buf[tid + s];
        __syncthreads();
    }
    float r = buf[0]; __syncthreads();
    return r;
}

template<typename Tin>
__global__ __launch_bounds__(256) void ln_kernel(const Tin* __restrict__ x,
                                                 const float* __restrict__ w,
                                                 const float* __restrict__ b,
                                                 short* __restrict__ out)
{
    __shared__ float buf[256];
    int row = blockIdx.x, tid = threadIdx.x;
    const Tin* xr = x + (size_t)row*DM;
    float v[3];
    float s = 0.f, s2 = 0.f;
    #pragma unroll
    for (int i = 0; i < 3; i++){
        float t = tof(xr[tid + 256*i]);
        v[i] = t; s += t; s2 += t*t;
    }
    float sum  = block_reduce_sum(s,  buf);
    float sum2 = block_reduce_sum(s2, buf);
    float mean = sum * (1.0f/DM);
    float var  = sum2 * (1.0f/DM) - mean*mean;
    float rstd = rsqrtf(var + LN_EPS);
    #pragma unroll
    for (int i = 0; i < 3; i++){
        int c = tid + 256*i;
        out[(size_t)row*DM + c] = f2bs((v[i] - mean)*rstd*w[c] + b[c]);
    }
}

// Swizzle (BK=32, 64B rows): data(row m, seg s) stored at seg c = s ^ ((m>>1)&3).
// Frag read bank-group = (4(m&1) + (quad^((m>>1)&3))) mod 8 -> all 8 groups over 8 lanes,
// 2-way over 16 lanes (free). Staged via gload16: lane l -> row l>>2, stored seg l&3,
// so the GLOBAL seg for lane l is (l&3) ^ (((l>>2)>>1)&3).

// ---------------- MFMA B^T GEMM, 128x128 tile, BK=32 double-buffered ----------------
// EPI: 1=gelu. RES: 2=fp32 residual. OUT: 0 bf16, 1 fp32.
// SPLITV: cols<1536 -> Cp (stride 1536), cols>=1536 -> Cp2 (stride 768), both bf16.
template<int EPI, int RES, int OUT, int SPLITV>
__global__ __launch_bounds__(256) void gemm_bt(const short* __restrict__ A,
                                               const short* __restrict__ Bt,
                                               const float* __restrict__ bias,
                                               const void* __restrict__ resp,
                                               void* __restrict__ Cp,
                                               void* __restrict__ Cp2,
                                               int N, int K)
{
    __shared__ alignas(16) short As[2][128*32];
    __shared__ alignas(16) short Bs[2][128*32];
    int tid = threadIdx.x, lane = tid & 63, w = tid >> 6;
    int l15 = lane & 15, quad = lane >> 4;
    int m_base = blockIdx.y*128, n_base = blockIdx.x*128;

    int r4 = lane >> 2;
    int sG = ((lane & 3) ^ ((r4 >> 1) & 3)) * 8;
    const short* gA0 = A  + (size_t)(m_base + 32*w      + r4)*K + sG;
    const short* gA1 = A  + (size_t)(m_base + 32*w + 16 + r4)*K + sG;
    const short* gB0 = Bt + (size_t)(n_base + 32*w      + r4)*K + sG;
    const short* gB1 = Bt + (size_t)(n_base + 32*w + 16 + r4)*K + sG;

    int mrow0 = (w >> 1)*64, ncol0 = (w & 1)*64;
    f32x4 acc[4][4] = {};

    gload16(gA0, &As[0][(2*w)*512]);
    gload16(gA1, &As[0][(2*w+1)*512]);
    gload16(gB0, &Bs[0][(2*w)*512]);
    gload16(gB1, &Bs[0][(2*w+1)*512]);

    int nk = K >> 5;
    for (int ki = 0; ki < nk; ki++){
        __syncthreads();
        int cur = ki & 1, nxt = cur ^ 1;
        if (ki + 1 < nk){
            int off = (ki + 1) << 5;
            gload16(gA0 + off, &As[nxt][(2*w)*512]);
            gload16(gA1 + off, &As[nxt][(2*w+1)*512]);
            gload16(gB0 + off, &Bs[nxt][(2*w)*512]);
            gload16(gB1 + off, &Bs[nxt][(2*w+1)*512]);
        }
        bf16x8 af[4], bfr[4];
        #pragma unroll
        for (int i = 0; i < 4; i++){
            int m = mrow0 + 16*i + l15;
            af[i] = *(const bf16x8*)(&As[cur][m*32 + ((quad ^ ((m >> 1) & 3))*8)]);
        }
        #pragma unroll
        for (int j = 0; j < 4; j++){
            int n = ncol0 + 16*j + l15;
            bfr[j] = *(const bf16x8*)(&Bs[cur][n*32 + ((quad ^ ((n >> 1) & 3))*8)]);
        }
        #pragma unroll
        for (int i = 0; i < 4; i++)
            #pragma unroll
            for (int j = 0; j < 4; j++)
                acc[i][j] = MFMA16(af[i], bfr[j], acc[i][j]);
    }

    #pragma unroll
    for (int i = 0; i < 4; i++){
        #pragma unroll
        for (int j = 0; j < 4; j++){
            #pragma unroll
            for (int r = 0; r < 4; r++){
                size_t row = (size_t)(m_base + mrow0 + 16*i + quad*4 + r);
                int    col = n_base + ncol0 + 16*j + l15;
                float v = acc[i][j][r] + bias[col];
                if (EPI == 1) v = gelu_f(v);
                if (RES == 2) v += ((const float*)resp)[row*N + col];
                if (SPLITV){
                    if (col < 1536) ((short*)Cp )[row*1536 + col]        = f2bs(v);
                    else            ((short*)Cp2)[row*768  + col - 1536] = f2bs(v);
                } else if (OUT == 0) ((short*)Cp)[row*N + col] = f2bs(v);
                else                 ((float*)Cp)[row*N + col] = v;
            }
        }
    }
}

// ---------------- thin MFMA GEMM: 128x64 tile, BK=32 dbuf (O-projection) ----------------
// RES=2 fp32 residual; OUT=0 bf16.
template<int EPI, int RES, int OUT>
__global__ __launch_bounds__(256) void gemm_bt_thin(const short* __restrict__ A,
                                                    const short* __restrict__ Bt,
                                                    const float* __restrict__ bias,
                                                    const void* __restrict__ resp,
                                                    void* __restrict__ Cp,
                                                    int N, int K)
{
    __shared__ alignas(16) short As[2][128*32];
    __shared__ alignas(16) short Bs[2][64*32];
    int tid = threadIdx.x, lane = tid & 63, w = tid >> 6;
    int l15 = lane & 15, quad = lane >> 4;
    int m_base = blockIdx.y*128, n_base = blockIdx.x*64;

    int r4 = lane >> 2;
    int sG = ((lane & 3) ^ ((r4 >> 1) & 3)) * 8;
    const short* gA0 = A  + (size_t)(m_base + 32*w      + r4)*K + sG;
    const short* gA1 = A  + (size_t)(m_base + 32*w + 16 + r4)*K + sG;
    const short* gB0 = Bt + (size_t)(n_base + 16*w      + r4)*K + sG;

    f32x4 acc[2][4] = {};

    gload16(gA0, &As[0][(2*w)*512]);
    gload16(gA1, &As[0][(2*w+1)*512]);
    gload16(gB0, &Bs[0][w*512]);

    int nk = K >> 5;
    for (int ki = 0; ki < nk; ki++){
        __syncthreads();
        int cur = ki & 1, nxt = cur ^ 1;
        if (ki + 1 < nk){
            int off = (ki + 1) << 5;
            gload16(gA0 + off, &As[nxt][(2*w)*512]);
            gload16(gA1 + off, &As[nxt][(2*w+1)*512]);
            gload16(gB0 + off, &Bs[nxt][w*512]);
        }
        bf16x8 af[2], bfr[4];
        #pragma unroll
        for (int i = 0; i < 2; i++){
            int m = 32*w + 16*i + l15;
            af[i] = *(const bf16x8*)(&As[cur][m*32 + ((quad ^ ((m >> 1) & 3))*8)]);
        }
        #pragma unroll
        for (int j = 0; j < 4; j++){
            int n = 16*j + l15;
            bfr[j] = *(const bf16x8*)(&Bs[cur][n*32 + ((quad ^ ((n >> 1) & 3))*8)]);
        }
        #pragma unroll
        for (int i = 0; i < 2; i++)
            #pragma unroll
            for (int j = 0; j < 4; j++)
                acc[i][j] = MFMA16(af[i], bfr[j], acc[i][j]);
    }

    #pragma unroll
    for (int i = 0; i < 2; i++){
        #pragma unroll
        for (int j = 0; j < 4; j++){
            #pragma unroll
            for (int r = 0; r < 4; r++){
                size_t row = (size_t)(m_base + 32*w + 16*i + quad*4 + r);
                int    col = n_base + 16*j + l15;
                float v = acc[i][j][r] + bias[col];
                if (EPI == 1) v = gelu_f(v);
                if (RES == 2) v += ((const float*)resp)[row*N + col];
                if (OUT == 0) ((short*)Cp)[row*N + col] = f2bs(v);
                else          ((float*)Cp)[row*N + col] = v;
            }
        }
    }
}

// ---------------- MLP-out: 128x64 tile, split-K over blockIdx.z, atomic fp32 out ----------
// Cp must be pre-zeroed. z==0 folds bias + bf16 residual. KS = K/gridDim.z.
__global__ __launch_bounds__(256) void gemm_out_sk(const short* __restrict__ A,
                                                   const short* __restrict__ Bt,
                                                   const float* __restrict__ bias,
                                                   const short* __restrict__ resp,
                                                   float* __restrict__ Cp,
                                                   int N, int K, int KS)
{
    __shared__ alignas(16) short As[2][128*32];
    __shared__ alignas(16) short Bs[2][64*32];
    int tid = threadIdx.x, lane = tid & 63, w = tid >> 6;
    int l15 = lane & 15, quad = lane >> 4;
    int m_base = blockIdx.y*128, n_base = blockIdx.x*64;
    int koff = blockIdx.z * KS;

    int r4 = lane >> 2;
    int sG = ((lane & 3) ^ ((r4 >> 1) & 3)) * 8;
    const short* gA0 = A  + (size_t)(m_base + 32*w      + r4)*K + koff + sG;
    const short* gA1 = A  + (size_t)(m_base + 32*w + 16 + r4)*K + koff + sG;
    const short* gB0 = Bt + (size_t)(n_base + 16*w      + r4)*K + koff + sG;

    f32x4 acc[2][4] = {};

    gload16(gA0, &As[0][(2*w)*512]);
    gload16(gA1, &As[0][(2*w+1)*512]);
    gload16(gB0, &Bs[0][w*512]);

    int nk = KS >> 5;
    for (int ki = 0; ki < nk; ki++){
        __syncthreads();
        int cur = ki & 1, nxt = cur ^ 1;
        if (ki + 1 < nk){
            int off = (ki + 1) << 5;
            gload16(gA0 + off, &As[nxt][(2*w)*512]);
            gload16(gA1 + off, &As[nxt][(2*w+1)*512]);
            gload16(gB0 + off, &Bs[nxt][w*512]);
        }
        bf16x8 af[2], bfr[4];
        #pragma unroll
        for (int i = 0; i < 2; i++){
            int m = 32*w + 16*i + l15;
            af[i] = *(const bf16x8*)(&As[cur][m*32 + ((quad ^ ((m >> 1) & 3))*8)]);
        }
        #pragma unroll
        for (int j = 0; j < 4; j++){
            int n = 16*j + l15;
            bfr[j] = *(const bf16x8*)(&Bs[cur][n*32 + ((quad ^ ((n >> 1) & 3))*8)]);
        }
        #pragma unroll
        for (int i = 0; i < 2; i++)
            #pragma unroll
            for (int j = 0; j < 4; j++)
                acc[i][j] = MFMA16(af[i], bfr[j], acc[i][j]);
    }

    bool first = (blockIdx.z == 0);
    #pragma unroll
    for (int i = 0; i < 2; i++){
        #pragma unroll
        for (int j = 0; j < 4; j++){
            #pragma unroll
            for (int r = 0; r < 4; r++){
                size_t row = (size_t)(m_base + 32*w + 16*i + quad*4 + r);
                int    col = n_base + 16*j + l15;
                float v = acc[i][j][r];
                if (first) v += bias[col] + us2f((unsigned short)resp[row*N + col]);
                unsafeAtomicAdd(&Cp[row*N + col], v);
            }
        }
    }
}

// ---------------- MFMA flash attention (K/V double-buffered, paired q-tiles) ----------------
__global__ __launch_bounds__(256) void flash_attn(const short* __restrict__ qk,
                                                  const short* __restrict__ vT,
                                                  short* __restrict__ z)
{
    __shared__ alignas(16) short U[4608];        // Q tile [64][64] swz / Ps [4][16][72]
    __shared__ alignas(16) short Ks[2][64*64];
    __shared__ alignas(16) short Vt[2][64*64];
    int p = blockIdx.x, h = blockIdx.y, b = blockIdx.z;
    int tid = threadIdx.x, lane = tid & 63, w = tid >> 6;
    int l15 = lane & 15, quad = lane >> 4;
    int r8 = lane >> 3, u8 = lane & 7;
    int useg = (u8 ^ r8) * 8;

    for (int phase = 0; phase < 2; phase++){
        int qt = phase ? (15 - p) : p;

        __syncthreads();
        #pragma unroll
        for (int c = 0; c < 2; c++){
            const short* g = qk + (size_t)(b*SEQ + qt*64 + 16*w + 8*c + r8)*1536 + h*DH + useg;
            gload16(g, U + (2*w + c)*512);
            const short* gk = qk + (size_t)(b*SEQ + 16*w + 8*c + r8)*1536 + DM + h*DH + useg;
            gload16(gk, &Ks[0][(2*w + c)*512]);
            const short* gv = vT + ((size_t)(b*NH + h)*DH + 16*w + 8*c + r8)*SEQ + useg;
            gload16(gv, &Vt[0][(2*w + c)*512]);
        }
        __syncthreads();

        bf16x8 aq[2];
        #pragma unroll
        for (int kk = 0; kk < 2; kk++)
            aq[kk] = *(const bf16x8*)(U + (16*w + l15)*64 + (((4*kk + quad) ^ (l15 & 7))*8));

        float m_state[4] = {-1e30f,-1e30f,-1e30f,-1e30f};
        float l_state[4] = {0.f,0.f,0.f,0.f};
        f32x4 o_acc[4] = {};
        int rg = qt*64 + w*16 + quad*4;

        for (int kt = 0; kt <= qt; ++kt){
            int cur = kt & 1, nxt = cur ^ 1;
            if (kt < qt){
                #pragma unroll
                for (int c = 0; c < 2; c++){
                    const short* gk = qk + (size_t)(b*SEQ + (kt+1)*64 + 16*w + 8*c + r8)*1536 + DM + h*DH + useg;
                    gload16(gk, &Ks[nxt][(2*w + c)*512]);
                    const short* gv = vT + ((size_t)(b*NH + h)*DH + 16*w + 8*c + r8)*SEQ + (kt+1)*64 + useg;
                    gload16(gv, &Vt[nxt][(2*w + c)*512]);
                }
            }

            f32x4 s[4] = {};
            #pragma unroll
            for (int kk = 0; kk < 2; kk++){
                int swz = ((4*kk + quad) ^ (l15 & 7)) * 8;
                #pragma unroll
                for (int j = 0; j < 4; j++){
                    bf16x8 bk = *(const bf16x8*)(&Ks[cur][(16*j + l15)*64 + swz]);
                    s[j] = MFMA16(aq[kk], bk, s[j]);
                }
            }

            bool diag = (kt == qt);
            #pragma unroll
            for (int j = 0; j < 4; j++){
                int col_g = kt*64 + 16*j + l15;
                #pragma unroll
                for (int r = 0; r < 4; r++){
                    float v = s[j][r] * 0.125f;
                    if (diag && col_g > rg + r) v = -1e30f;
                    s[j][r] = v;
                }
            }

            #pragma unroll
            for (int r = 0; r < 4; r++){
                float mx = fmaxf(fmaxf(s[0][r], s[1][r]), fmaxf(s[2][r], s[3][r]));
                #pragma unroll
                for (int d = 1; d < 16; d <<= 1) mx = fmaxf(mx, __shfl_xor(mx, d, 64));
                float m_new = fmaxf(m_state[r], mx);
                float alpha = __expf(m_state[r] - m_new);
                m_state[r] = m_new;
                float rs = 0.f;
                #pragma unroll
                for (int j = 0; j < 4; j++){
                    float pv = __expf(s[j][r] - m_new);
                    s[j][r] = pv; rs += pv;
                }
                #pragma unroll
                for (int d = 1; d < 16; d <<= 1) rs += __shfl_xor(rs, d, 64);
                l_state[r] = l_state[r]*alpha + rs;
                #pragma unroll
                for (int j = 0; j < 4; j++) o_acc[j][r] *= alpha;
            }

            #pragma unroll
            for (int j = 0; j < 4; j++)
                #pragma unroll
                for (int r = 0; r < 4; r++)
                    U[w*1152 + (quad*4 + r)*72 + 16*j + l15] = f2bs(s[j][r]);

            #pragma unroll
            for (int kk = 0; kk < 2; kk++){
                bf16x8 ap = *(const bf16x8*)(U + w*1152 + l15*72 + 32*kk + quad*8);
                int swz = ((4*kk + quad) ^ (l15 & 7)) * 8;
                #pragma unroll
                for (int j = 0; j < 4; j++){
                    bf16x8 bv = *(const bf16x8*)(&Vt[cur][(16*j + l15)*64 + swz]);
                    o_acc[j] = MFMA16(ap, bv, o_acc[j]);
                }
            }

            __syncthreads();
        }

        #pragma unroll
        for (int r = 0; r < 4; r++){
            float inv_l = 1.0f / l_state[r];
            size_t row = (size_t)(b*SEQ + rg + r);
            #pragma unroll
            for (int j = 0; j < 4; j++)
                z[row*DM + h*DH + 16*j + l15] = f2bs(o_acc[j][r] * inv_l);
        }
    }
}

// ---------------- launch ----------------
// ws map (59,778,048 B, lifetime-aliased):
//   A0 [0, 3538944)          wqkvT  -> WinT (A0+A1) after O-gemm
//   A1 [3538944, 4718592)    WOT
//   A2 [4718592, 4727808)    bias_qkv fp32
//   A3 [4727808, 29893632)   qk bf16 [qkv-gemm -> flash] -> hidden chunk (25.17MB) [MLP]
//   A4 [29893632, 42476544)  v_rm -> zbuf [flash -> O-gemm] -> ln2o [ln2 -> MLP]
//   A5 [42476544, 55059456)  ln1o -> vT [transpose_v -> flash] -> resid_mid bf16 [O-gemm -> end]
//   A6 [55059456, 59778048)  WoutT
// d_out: zeroed before MLP-out, then atomically accumulated (split-K).
extern "C" void kernel_launch(void* const* d_in, const int* in_sizes, int n_in,
                              void* d_out, int out_size, void* d_ws, size_t ws_size,
                              hipStream_t stream)
{
    const float* resid_pre = (const float*)d_in[0];
    const float* W_Q  = (const float*)d_in[1];
    const float* W_K  = (const float*)d_in[2];
    const float* W_V  = (const float*)d_in[3];
    const float* W_O  = (const float*)d_in[4];
    const float* b_Q  = (const float*)d_in[5];
    const float* b_K  = (const float*)d_in[6];
    const float* b_V  = (const float*)d_in[7];
    const float* b_O  = (const float*)d_in[8];
    const float* ln1w = (const float*)d_in[9];
    const float* ln1b = (const float*)d_in[10];
    const float* ln2w = (const float*)d_in[11];
    const float* ln2b = (const float*)d_in[12];
    const float* W_in = (const float*)d_in[13];
    const float* b_in = (const float*)d_in[14];
    const float* W_out= (const float*)d_in[15];
    const float* b_out= (const float*)d_in[16];

    char* ws = (char*)d_ws;
    short* wqkvT     = (short*)(ws);
    short* WOT       = (short*)(ws + 3538944);
    float* bias_qkv  = (float*)(ws + 4718592);
    short* WinT      = (short*)(ws);             // after O-gemm
    short* qk        = (short*)(ws + 4727808);   // A3
    short* hidden    = (short*)(ws + 4727808);   // A3 after flash
    short* v_rm      = (short*)(ws + 29893632);  // A4
    short* zbuf      = (short*)(ws + 29893632);  // A4 after transpose_v
    short* ln2o      = (short*)(ws + 29893632);  // A4 after O-gemm
    short* ln1o      = (short*)(ws + 42476544);  // A5
    short* vT        = (short*)(ws + 42476544);  // A5 after qkv-gemm
    short* resid_mid = (short*)(ws + 42476544);  // A5 after flash (vT dead post-flash)
    short* WoutT     = (short*)(ws + 55059456);  // A6

    // prep
    transpose_cvt_qkv<<<dim3(2, 24, 36), dim3(256), 0, stream>>>(W_Q, W_K, W_V, wqkvT);
    prep_qkv_bias<<<dim3(9), dim3(256), 0, stream>>>(b_Q, b_K, b_V, bias_qkv);
    transpose_cvt<<<dim3(24, 24), dim3(256), 0, stream>>>(W_O,   WOT,   DM,   DM);
    transpose_cvt<<<dim3(24, 96), dim3(256), 0, stream>>>(W_out, WoutT, DMLP, DM);

    // ln1 + QKV projection (split: Q,K -> qk[.][1536], V -> v_rm[.][768])
    ln_kernel<float><<<dim3(NTOK), dim3(256), 0, stream>>>(resid_pre, ln1w, ln1b, ln1o);
    gemm_bt<0,0,0,1><<<dim3(QKVN/128, NTOK/128), dim3(256), 0, stream>>>(
        ln1o, wqkvT, bias_qkv, nullptr, qk, v_rm, QKVN, DM);

    // V transpose (v_rm A4 -> vT A5; ln1o dead) then flash attention
    transpose_v<<<dim3(SEQ/64, NH, BATCH), dim3(256), 0, stream>>>(v_rm, vT);
    flash_attn<<<dim3(SEQ/128, NH, BATCH), dim3(256), 0, stream>>>(qk, vT, zbuf);

    // O projection + residual(resid_pre fp32) -> resid_mid bf16 (A5; vT dead)
    gemm_bt_thin<0,2,0><<<dim3(DM/64, NTOK/128), dim3(256), 0, stream>>>(
        zbuf, WOT, b_O, resid_pre, resid_mid, DM, DM);

    // W_in transpose (A0/A1 dead)
    transpose_cvt<<<dim3(96, 24), dim3(256), 0, stream>>>(W_in, WinT, DM, DMLP);

    // ln2: resid_mid bf16 -> ln2o (A4; zbuf dead)
    ln_kernel<short><<<dim3(NTOK), dim3(256), 0, stream>>>(resid_mid, ln2w, ln2b, ln2o);

    // zero d_out for atomic split-K accumulation
    hipMemsetAsync(d_out, 0, (size_t)NTOK*DM*4, stream);

    // MLP in 2 chunks of 4096 rows
    for (int chunk = 0; chunk < 2; chunk++){
        size_t r0 = (size_t)chunk * 4096;
        gemm_bt<1,0,0,0><<<dim3(DMLP/128, 4096/128), dim3(256), 0, stream>>>(
            ln2o + r0*DM, WinT, b_in, nullptr, hidden, nullptr, DMLP, DM);
        gemm_out_sk<<<dim3(DM/64, 4096/128, 2), dim3(256), 0, stream>>>(
            hidden, WoutT, b_out, resid_mid + r0*DM, (float*)d_out + r0*DM, DM, DMLP, DMLP/2);
    }
}

// Round 8
// 440.630 us; speedup vs baseline: 1.0452x; 1.0452x over previous
//
#include <hip/hip_runtime.h>
#include <hip/hip_bf16.h>
#include <math.h>

#define DM 768
#define NH 12
#define DH 64
#define DMLP 3072
#define BATCH 8
#define SEQ 1024
#define NTOK (BATCH*SEQ)
#define QKVN (3*DM)
#define LN_EPS 1e-5f

typedef __hip_bfloat16 bf16;
typedef __attribute__((ext_vector_type(8))) short bf16x8;
typedef __attribute__((ext_vector_type(4))) float f32x4;

#define MFMA16(a,b,c) __builtin_amdgcn_mfma_f32_16x16x32_bf16((a),(b),(c),0,0,0)

__device__ __forceinline__ float us2f(unsigned short u){
    unsigned int i = ((unsigned int)u) << 16; float f; __builtin_memcpy(&f, &i, 4); return f;
}
__device__ __forceinline__ short f2bs(float f){
    bf16 h = __float2bfloat16(f); short s; __builtin_memcpy(&s, &h, 2); return s;
}

// gelu_new(x) = x * sigmoid(2c(x + 0.044715 x^3)), c = sqrt(2/pi). ~7 VALU ops.
__device__ __forceinline__ float gelu_f(float x){
    float y = 1.5957691216057308f*(x + 0.044715f*x*x*x);
    return x * __builtin_amdgcn_rcpf(1.0f + __expf(-y));
}

// ---------------- transpose + fp32->bf16 convert: out[N][K] = in[K][N] ----------------
__global__ __launch_bounds__(256) void transpose_cvt(const float* __restrict__ in,
                                                     short* __restrict__ out,
                                                     int K, int N)
{
    __shared__ float t[32][33];
    int n0 = blockIdx.x*32, k0 = blockIdx.y*32;
    int tx = threadIdx.x & 31, ty = threadIdx.x >> 5;
    #pragma unroll
    for (int i = 0; i < 32; i += 8)
        t[ty+i][tx] = in[(size_t)(k0+ty+i)*N + n0+tx];
    __syncthreads();
    #pragma unroll
    for (int i = 0; i < 32; i += 8)
        out[(size_t)(n0+ty+i)*K + k0+tx] = f2bs(t[tx][ty+i]);
}

// qkv weights: W_{q,k,v}[h][k][e] -> wqkvT[n = which*768 + h*64 + e][k], bf16
__global__ __launch_bounds__(256) void transpose_cvt_qkv(const float* __restrict__ Wq,
                                                         const float* __restrict__ Wk,
                                                         const float* __restrict__ Wv,
                                                         short* __restrict__ out)
{
    __shared__ float t[32][33];
    int zz = blockIdx.z;
    int which = zz / 12, h = zz % 12;
    const float* in = (which == 0 ? Wq : which == 1 ? Wk : Wv) + (size_t)h*DM*DH;
    short* o = out + ((size_t)which*DM + h*DH)*DM;
    int n0 = blockIdx.x*32, k0 = blockIdx.y*32;
    int tx = threadIdx.x & 31, ty = threadIdx.x >> 5;
    #pragma unroll
    for (int i = 0; i < 32; i += 8)
        t[ty+i][tx] = in[(size_t)(k0+ty+i)*DH + n0+tx];
    __syncthreads();
    #pragma unroll
    for (int i = 0; i < 32; i += 8)
        o[(size_t)(n0+ty+i)*DM + k0+tx] = f2bs(t[tx][ty+i]);
}

// concat b_Q|b_K|b_V -> [2304] fp32
__global__ __launch_bounds__(256) void prep_qkv_bias(const float* bQ, const float* bK, const float* bV,
                                                     float* __restrict__ out)
{
    int idx = blockIdx.x*256 + threadIdx.x;
    if (idx >= QKVN) return;
    int which = idx / DM, hc = idx % DM;
    const float* b = (which == 0) ? bQ : ((which == 1) ? bK : bV);
    out[idx] = b[hc];
}

// v_rm [8192][768] bf16 -> vT [(b*12+h)*64 + d][1024] bf16
__global__ __launch_bounds__(256) void transpose_v(const short* __restrict__ v_rm,
                                                   short* __restrict__ vT)
{
    __shared__ short t[64][65];
    int st = blockIdx.x, h = blockIdx.y, b = blockIdx.z;
    int tok = threadIdx.x >> 2, seg = (threadIdx.x & 3)*16;
    const short* src = v_rm + (size_t)(b*SEQ + st*64 + tok)*DM + h*DH + seg;
    bf16x8 a0 = *(const bf16x8*)src;
    bf16x8 a1 = *(const bf16x8*)(src + 8);
    #pragma unroll
    for (int i = 0; i < 8; i++) t[seg + i][tok]     = a0[i];
    #pragma unroll
    for (int i = 0; i < 8; i++) t[seg + 8 + i][tok] = a1[i];
    __syncthreads();
    int d = threadIdx.x >> 2; int sk = (threadIdx.x & 3)*16;
    short* dst = vT + ((size_t)(b*NH + h)*DH + d)*SEQ + st*64 + sk;
    bf16x8 w0, w1;
    #pragma unroll
    for (int i = 0; i < 8; i++) w0[i] = t[d][sk + i];
    #pragma unroll
    for (int i = 0; i < 8; i++) w1[i] = t[d][sk + 8 + i];
    *(bf16x8*)dst = w0;
    *(bf16x8*)(dst + 8) = w1;
}

// ---------------- layernorm (fp32 in, bf16 out) ----------------
__device__ __forceinline__ float block_reduce_sum(float v, float* buf){
    int tid = threadIdx.x;
    buf[tid] = v; __syncthreads();
    for (int s = 128; s > 0; s >>= 1){
        if (tid < s) buf[tid] += buf[tid + s];
        __syncthreads();
    }
    float r = buf[0]; __syncthreads();
    return r;
}

__global__ __launch_bounds__(256) void ln_kernel(const float* __restrict__ x,
                                                 const float* __restrict__ w,
                                                 const float* __restrict__ b,
                                                 short* __restrict__ out)
{
    __shared__ float buf[256];
    int row = blockIdx.x, tid = threadIdx.x;
    const float* xr = x + (size_t)row*DM;
    float v[3];
    float s = 0.f, s2 = 0.f;
    #pragma unroll
    for (int i = 0; i < 3; i++){
        float t = xr[tid + 256*i];
        v[i] = t; s += t; s2 += t*t;
    }
    float sum  = block_reduce_sum(s,  buf);
    float sum2 = block_reduce_sum(s2, buf);
    float mean = sum * (1.0f/DM);
    float var  = sum2 * (1.0f/DM) - mean*mean;
    float rstd = rsqrtf(var + LN_EPS);
    #pragma unroll
    for (int i = 0; i < 3; i++){
        int c = tid + 256*i;
        out[(size_t)row*DM + c] = f2bs((v[i] - mean)*rstd*w[c] + b[c]);
    }
}

// Swizzle (BK=32, 64B rows): data(row m, seg s) stored at seg c = s ^ ((m>>1)&3).
// Staging lane l -> row r4=l>>2, stored seg l&3, global seg (l&3)^((r4>>1)&3).
// Frag read covers all 8 bank-groups (r7-verified: 0 conflicts).

// ---------------- MFMA B^T GEMM, 128x128 tile, BK=32, REGISTER-staged dbuf --------------
// Loads for tile k+1 issue before the MFMAs of tile k; vmcnt-wait lands at the ds_write
// AFTER the MFMAs, so global latency overlaps compute; barrier only drains ds_writes.
// EPI: 1=gelu. RES: 2=fp32 residual. OUT: 0 bf16, 1 fp32.
// SPLITV: cols<1536 -> Cp (stride 1536), cols>=1536 -> Cp2 (stride 768), both bf16.
template<int EPI, int RES, int OUT, int SPLITV>
__global__ __launch_bounds__(256) void gemm_bt(const short* __restrict__ A,
                                               const short* __restrict__ Bt,
                                               const float* __restrict__ bias,
                                               const void* __restrict__ resp,
                                               void* __restrict__ Cp,
                                               void* __restrict__ Cp2,
                                               int N, int K)
{
    __shared__ alignas(16) short As[2][128*32];
    __shared__ alignas(16) short Bs[2][128*32];
    int tid = threadIdx.x, lane = tid & 63, w = tid >> 6;
    int l15 = lane & 15, quad = lane >> 4;
    int m_base = blockIdx.y*128, n_base = blockIdx.x*128;

    int r4 = lane >> 2;
    int sG = ((lane & 3) ^ ((r4 >> 1) & 3)) * 8;
    const short* gA0 = A  + (size_t)(m_base + 32*w      + r4)*K + sG;
    const short* gA1 = A  + (size_t)(m_base + 32*w + 16 + r4)*K + sG;
    const short* gB0 = Bt + (size_t)(n_base + 32*w      + r4)*K + sG;
    const short* gB1 = Bt + (size_t)(n_base + 32*w + 16 + r4)*K + sG;
    int la0 = (2*w)*512 + lane*8, la1 = (2*w+1)*512 + lane*8;

    int mrow0 = (w >> 1)*64, ncol0 = (w & 1)*64;
    f32x4 acc[4][4] = {};

    bf16x8 pa0 = *(const bf16x8*)gA0, pa1 = *(const bf16x8*)gA1;
    bf16x8 pb0 = *(const bf16x8*)gB0, pb1 = *(const bf16x8*)gB1;
    *(bf16x8*)&As[0][la0] = pa0; *(bf16x8*)&As[0][la1] = pa1;
    *(bf16x8*)&Bs[0][la0] = pb0; *(bf16x8*)&Bs[0][la1] = pb1;
    __syncthreads();

    int nk = K >> 5;
    for (int ki = 0; ki < nk; ki++){
        int cur = ki & 1, nxt = cur ^ 1;
        if (ki + 1 < nk){
            int off = (ki + 1) << 5;
            pa0 = *(const bf16x8*)(gA0 + off); pa1 = *(const bf16x8*)(gA1 + off);
            pb0 = *(const bf16x8*)(gB0 + off); pb1 = *(const bf16x8*)(gB1 + off);
        }
        bf16x8 af[4], bfr[4];
        #pragma unroll
        for (int i = 0; i < 4; i++){
            int m = mrow0 + 16*i + l15;
            af[i] = *(const bf16x8*)(&As[cur][m*32 + ((quad ^ ((m >> 1) & 3))*8)]);
        }
        #pragma unroll
        for (int j = 0; j < 4; j++){
            int n = ncol0 + 16*j + l15;
            bfr[j] = *(const bf16x8*)(&Bs[cur][n*32 + ((quad ^ ((n >> 1) & 3))*8)]);
        }
        #pragma unroll
        for (int i = 0; i < 4; i++)
            #pragma unroll
            for (int j = 0; j < 4; j++)
                acc[i][j] = MFMA16(af[i], bfr[j], acc[i][j]);
        if (ki + 1 < nk){
            *(bf16x8*)&As[nxt][la0] = pa0; *(bf16x8*)&As[nxt][la1] = pa1;
            *(bf16x8*)&Bs[nxt][la0] = pb0; *(bf16x8*)&Bs[nxt][la1] = pb1;
        }
        __syncthreads();
    }

    #pragma unroll
    for (int i = 0; i < 4; i++){
        #pragma unroll
        for (int j = 0; j < 4; j++){
            #pragma unroll
            for (int r = 0; r < 4; r++){
                size_t row = (size_t)(m_base + mrow0 + 16*i + quad*4 + r);
                int    col = n_base + ncol0 + 16*j + l15;
                float v = acc[i][j][r] + bias[col];
                if (EPI == 1) v = gelu_f(v);
                if (RES == 2) v += ((const float*)resp)[row*N + col];
                if (SPLITV){
                    if (col < 1536) ((short*)Cp )[row*1536 + col]        = f2bs(v);
                    else            ((short*)Cp2)[row*768  + col - 1536] = f2bs(v);
                } else if (OUT == 0) ((short*)Cp)[row*N + col] = f2bs(v);
                else                 ((float*)Cp)[row*N + col] = v;
            }
        }
    }
}

// ---------------- thin MFMA GEMM: 128x64 tile, BK=32, register-staged dbuf --------------
template<int EPI, int RES, int OUT>
__global__ __launch_bounds__(256) void gemm_bt_thin(const short* __restrict__ A,
                                                    const short* __restrict__ Bt,
                                                    const float* __restrict__ bias,
                                                    const void* __restrict__ resp,
                                                    void* __restrict__ Cp,
                                                    int N, int K)
{
    __shared__ alignas(16) short As[2][128*32];
    __shared__ alignas(16) short Bs[2][64*32];
    int tid = threadIdx.x, lane = tid & 63, w = tid >> 6;
    int l15 = lane & 15, quad = lane >> 4;
    int m_base = blockIdx.y*128, n_base = blockIdx.x*64;

    int r4 = lane >> 2;
    int sG = ((lane & 3) ^ ((r4 >> 1) & 3)) * 8;
    const short* gA0 = A  + (size_t)(m_base + 32*w      + r4)*K + sG;
    const short* gA1 = A  + (size_t)(m_base + 32*w + 16 + r4)*K + sG;
    const short* gB0 = Bt + (size_t)(n_base + 16*w      + r4)*K + sG;
    int la0 = (2*w)*512 + lane*8, la1 = (2*w+1)*512 + lane*8;
    int lb0 = w*512 + lane*8;

    f32x4 acc[2][4] = {};

    bf16x8 pa0 = *(const bf16x8*)gA0, pa1 = *(const bf16x8*)gA1;
    bf16x8 pb0 = *(const bf16x8*)gB0;
    *(bf16x8*)&As[0][la0] = pa0; *(bf16x8*)&As[0][la1] = pa1;
    *(bf16x8*)&Bs[0][lb0] = pb0;
    __syncthreads();

    int nk = K >> 5;
    for (int ki = 0; ki < nk; ki++){
        int cur = ki & 1, nxt = cur ^ 1;
        if (ki + 1 < nk){
            int off = (ki + 1) << 5;
            pa0 = *(const bf16x8*)(gA0 + off); pa1 = *(const bf16x8*)(gA1 + off);
            pb0 = *(const bf16x8*)(gB0 + off);
        }
        bf16x8 af[2], bfr[4];
        #pragma unroll
        for (int i = 0; i < 2; i++){
            int m = 32*w + 16*i + l15;
            af[i] = *(const bf16x8*)(&As[cur][m*32 + ((quad ^ ((m >> 1) & 3))*8)]);
        }
        #pragma unroll
        for (int j = 0; j < 4; j++){
            int n = 16*j + l15;
            bfr[j] = *(const bf16x8*)(&Bs[cur][n*32 + ((quad ^ ((n >> 1) & 3))*8)]);
        }
        #pragma unroll
        for (int i = 0; i < 2; i++)
            #pragma unroll
            for (int j = 0; j < 4; j++)
                acc[i][j] = MFMA16(af[i], bfr[j], acc[i][j]);
        if (ki + 1 < nk){
            *(bf16x8*)&As[nxt][la0] = pa0; *(bf16x8*)&As[nxt][la1] = pa1;
            *(bf16x8*)&Bs[nxt][lb0] = pb0;
        }
        __syncthreads();
    }

    #pragma unroll
    for (int i = 0; i < 2; i++){
        #pragma unroll
        for (int j = 0; j < 4; j++){
            #pragma unroll
            for (int r = 0; r < 4; r++){
                size_t row = (size_t)(m_base + 32*w + 16*i + quad*4 + r);
                int    col = n_base + 16*j + l15;
                float v = acc[i][j][r] + bias[col];
                if (EPI == 1) v = gelu_f(v);
                if (RES == 2) v += ((const float*)resp)[row*N + col];
                if (OUT == 0) ((short*)Cp)[row*N + col] = f2bs(v);
                else          ((float*)Cp)[row*N + col] = v;
            }
        }
    }
}

// ---------------- MFMA flash attention: register-staged K/V dbuf, paired q-tiles -------
// qk [8192][1536]: cols [0,768) Q, [768,1536) K (col h*64+e). vT [(b*12+h)*64+d][1024].
__global__ __launch_bounds__(256) void flash_attn(const short* __restrict__ qk,
                                                  const short* __restrict__ vT,
                                                  short* __restrict__ z)
{
    __shared__ alignas(16) short U[4608];        // Q tile [64][64] swz / Ps [4][16][72]
    __shared__ alignas(16) short Ks[2][64*64];
    __shared__ alignas(16) short Vt[2][64*64];
    int p = blockIdx.x, h = blockIdx.y, b = blockIdx.z;
    int tid = threadIdx.x, lane = tid & 63, w = tid >> 6;
    int l15 = lane & 15, quad = lane >> 4;
    int r8 = lane >> 3, u8 = lane & 7;
    int useg = (u8 ^ r8) * 8;
    int lc0 = (2*w)*512 + lane*8, lc1 = (2*w+1)*512 + lane*8;

    const short* kbase = qk + DM + h*DH;
    const short* vbase = vT + (size_t)(b*NH + h)*DH*SEQ;

    for (int phase = 0; phase < 2; phase++){
        int qt = phase ? (15 - p) : p;

        __syncthreads();   // prior phase's LDS readers done
        {
            bf16x8 q0 = *(const bf16x8*)(qk + (size_t)(b*SEQ + qt*64 + 16*w + r8)*1536 + h*DH + useg);
            bf16x8 q1 = *(const bf16x8*)(qk + (size_t)(b*SEQ + qt*64 + 16*w + 8 + r8)*1536 + h*DH + useg);
            bf16x8 k0 = *(const bf16x8*)(kbase + (size_t)(b*SEQ + 16*w + r8)*1536 + useg);
            bf16x8 k1 = *(const bf16x8*)(kbase + (size_t)(b*SEQ + 16*w + 8 + r8)*1536 + useg);
            bf16x8 v0 = *(const bf16x8*)(vbase + (size_t)(16*w + r8)*SEQ + useg);
            bf16x8 v1 = *(const bf16x8*)(vbase + (size_t)(16*w + 8 + r8)*SEQ + useg);
            *(bf16x8*)&U[lc0] = q0;        *(bf16x8*)&U[lc1] = q1;
            *(bf16x8*)&Ks[0][lc0] = k0;    *(bf16x8*)&Ks[0][lc1] = k1;
            *(bf16x8*)&Vt[0][lc0] = v0;    *(bf16x8*)&Vt[0][lc1] = v1;
        }
        __syncthreads();

        bf16x8 aq[2];
        #pragma unroll
        for (int kk = 0; kk < 2; kk++)
            aq[kk] = *(const bf16x8*)(U + (16*w + l15)*64 + (((4*kk + quad) ^ (l15 & 7))*8));

        float m_state[4] = {-1e30f,-1e30f,-1e30f,-1e30f};
        float l_state[4] = {0.f,0.f,0.f,0.f};
        f32x4 o_acc[4] = {};
        int rg = qt*64 + w*16 + quad*4;

        for (int kt = 0; kt <= qt; ++kt){
            int cur = kt & 1, nxt = cur ^ 1;
            bf16x8 pk0, pk1, pv0, pv1;
            if (kt < qt){   // prefetch next K/V tile into REGISTERS (in flight over compute)
                pk0 = *(const bf16x8*)(kbase + (size_t)(b*SEQ + (kt+1)*64 + 16*w + r8)*1536 + useg);
                pk1 = *(const bf16x8*)(kbase + (size_t)(b*SEQ + (kt+1)*64 + 16*w + 8 + r8)*1536 + useg);
                pv0 = *(const bf16x8*)(vbase + (size_t)(16*w + r8)*SEQ + (kt+1)*64 + useg);
                pv1 = *(const bf16x8*)(vbase + (size_t)(16*w + 8 + r8)*SEQ + (kt+1)*64 + useg);
            }

            f32x4 s[4] = {};
            #pragma unroll
            for (int kk = 0; kk < 2; kk++){
                int swz = ((4*kk + quad) ^ (l15 & 7)) * 8;
                #pragma unroll
                for (int j = 0; j < 4; j++){
                    bf16x8 bk = *(const bf16x8*)(&Ks[cur][(16*j + l15)*64 + swz]);
                    s[j] = MFMA16(aq[kk], bk, s[j]);
                }
            }

            bool diag = (kt == qt);
            #pragma unroll
            for (int j = 0; j < 4; j++){
                int col_g = kt*64 + 16*j + l15;
                #pragma unroll
                for (int r = 0; r < 4; r++){
                    float v = s[j][r] * 0.125f;
                    if (diag && col_g > rg + r) v = -1e30f;
                    s[j][r] = v;
                }
            }

            #pragma unroll
            for (int r = 0; r < 4; r++){
                float mx = fmaxf(fmaxf(s[0][r], s[1][r]), fmaxf(s[2][r], s[3][r]));
                #pragma unroll
                for (int d = 1; d < 16; d <<= 1) mx = fmaxf(mx, __shfl_xor(mx, d, 64));
                float m_new = fmaxf(m_state[r], mx);
                float alpha = __expf(m_state[r] - m_new);
                m_state[r] = m_new;
                float rs = 0.f;
                #pragma unroll
                for (int j = 0; j < 4; j++){
                    float pv = __expf(s[j][r] - m_new);
                    s[j][r] = pv; rs += pv;
                }
                #pragma unroll
                for (int d = 1; d < 16; d <<= 1) rs += __shfl_xor(rs, d, 64);
                l_state[r] = l_state[r]*alpha + rs;
                #pragma unroll
                for (int j = 0; j < 4; j++) o_acc[j][r] *= alpha;
            }

            #pragma unroll
            for (int j = 0; j < 4; j++)
                #pragma unroll
                for (int r = 0; r < 4; r++)
                    U[w*1152 + (quad*4 + r)*72 + 16*j + l15] = f2bs(s[j][r]);

            #pragma unroll
            for (int kk = 0; kk < 2; kk++){
                bf16x8 ap = *(const bf16x8*)(U + w*1152 + l15*72 + 32*kk + quad*8);
                int swz = ((4*kk + quad) ^ (l15 & 7)) * 8;
                #pragma unroll
                for (int j = 0; j < 4; j++){
                    bf16x8 bv = *(const bf16x8*)(&Vt[cur][(16*j + l15)*64 + swz]);
                    o_acc[j] = MFMA16(ap, bv, o_acc[j]);
                }
            }

            if (kt < qt){   // commit prefetched tile; vmcnt-wait lands here, after compute
                *(bf16x8*)&Ks[nxt][lc0] = pk0;  *(bf16x8*)&Ks[nxt][lc1] = pk1;
                *(bf16x8*)&Vt[nxt][lc0] = pv0;  *(bf16x8*)&Vt[nxt][lc1] = pv1;
            }
            __syncthreads();
        }

        #pragma unroll
        for (int r = 0; r < 4; r++){
            float inv_l = 1.0f / l_state[r];
            size_t row = (size_t)(b*SEQ + rg + r);
            #pragma unroll
            for (int j = 0; j < 4; j++)
                z[row*DM + h*DH + 16*j + l15] = f2bs(o_acc[j][r] * inv_l);
        }
    }
}

// ---------------- launch ----------------
// ws map (59,778,048 B, lifetime-aliased; r5-proven dataflow):
//   A0 [0, 3538944)          wqkvT  -> WinT (A0+A1) after O-gemm
//   A1 [3538944, 4718592)    WOT
//   A2 [4718592, 4727808)    bias_qkv fp32
//   A3 [4727808, 29893632)   qk bf16 [qkv-gemm -> flash] -> hidden chunk (25.17MB) [MLP]
//   A4 [29893632, 42476544)  v_rm [qkv-gemm -> transpose_v] -> zbuf [flash -> O-gemm]
//   A5 [42476544, 55059456)  ln1o -> vT [transpose_v -> flash] -> ln2o [ln2 -> MLP]
//   A6 [55059456, 59778048)  WoutT
// resid_mid lives in d_out (fp32): O-gemm writes it, ln2 reads it, final gemm adds in place.
extern "C" void kernel_launch(void* const* d_in, const int* in_sizes, int n_in,
                              void* d_out, int out_size, void* d_ws, size_t ws_size,
                              hipStream_t stream)
{
    const float* resid_pre = (const float*)d_in[0];
    const float* W_Q  = (const float*)d_in[1];
    const float* W_K  = (const float*)d_in[2];
    const float* W_V  = (const float*)d_in[3];
    const float* W_O  = (const float*)d_in[4];
    const float* b_Q  = (const float*)d_in[5];
    const float* b_K  = (const float*)d_in[6];
    const float* b_V  = (const float*)d_in[7];
    const float* b_O  = (const float*)d_in[8];
    const float* ln1w = (const float*)d_in[9];
    const float* ln1b = (const float*)d_in[10];
    const float* ln2w = (const float*)d_in[11];
    const float* ln2b = (const float*)d_in[12];
    const float* W_in = (const float*)d_in[13];
    const float* b_in = (const float*)d_in[14];
    const float* W_out= (const float*)d_in[15];
    const float* b_out= (const float*)d_in[16];

    char* ws = (char*)d_ws;
    short* wqkvT    = (short*)(ws);
    short* WOT      = (short*)(ws + 3538944);
    float* bias_qkv = (float*)(ws + 4718592);
    short* WinT     = (short*)(ws);             // after O-gemm
    short* qk       = (short*)(ws + 4727808);   // A3
    short* hidden   = (short*)(ws + 4727808);   // A3 after flash
    short* v_rm     = (short*)(ws + 29893632);  // A4
    short* zbuf     = (short*)(ws + 29893632);  // A4 after transpose_v
    short* ln1o     = (short*)(ws + 42476544);  // A5
    short* vT       = (short*)(ws + 42476544);  // A5 after qkv-gemm
    short* ln2o     = (short*)(ws + 42476544);  // A5 after flash
    short* WoutT    = (short*)(ws + 55059456);  // A6

    // prep
    transpose_cvt_qkv<<<dim3(2, 24, 36), dim3(256), 0, stream>>>(W_Q, W_K, W_V, wqkvT);
    prep_qkv_bias<<<dim3(9), dim3(256), 0, stream>>>(b_Q, b_K, b_V, bias_qkv);
    transpose_cvt<<<dim3(24, 24), dim3(256), 0, stream>>>(W_O,   WOT,   DM,   DM);
    transpose_cvt<<<dim3(24, 96), dim3(256), 0, stream>>>(W_out, WoutT, DMLP, DM);

    // ln1 + QKV projection (split: Q,K -> qk[.][1536], V -> v_rm[.][768])
    ln_kernel<<<dim3(NTOK), dim3(256), 0, stream>>>(resid_pre, ln1w, ln1b, ln1o);
    gemm_bt<0,0,0,1><<<dim3(QKVN/128, NTOK/128), dim3(256), 0, stream>>>(
        ln1o, wqkvT, bias_qkv, nullptr, qk, v_rm, QKVN, DM);

    // V transpose then flash attention
    transpose_v<<<dim3(SEQ/64, NH, BATCH), dim3(256), 0, stream>>>(v_rm, vT);
    flash_attn<<<dim3(SEQ/128, NH, BATCH), dim3(256), 0, stream>>>(qk, vT, zbuf);

    // O projection + residual(resid_pre fp32) -> d_out fp32
    gemm_bt_thin<0,2,1><<<dim3(DM/64, NTOK/128), dim3(256), 0, stream>>>(
        zbuf, WOT, b_O, resid_pre, d_out, DM, DM);

    // W_in transpose (A0/A1 dead)
    transpose_cvt<<<dim3(96, 24), dim3(256), 0, stream>>>(W_in, WinT, DM, DMLP);

    // ln2 on d_out (fp32)
    ln_kernel<<<dim3(NTOK), dim3(256), 0, stream>>>((const float*)d_out, ln2w, ln2b, ln2o);

    // MLP in 2 chunks of 4096 rows; final gemm reads+writes d_out in place
    for (int chunk = 0; chunk < 2; chunk++){
        size_t r0 = (size_t)chunk * 4096;
        gemm_bt<1,0,0,0><<<dim3(DMLP/128, 4096/128), dim3(256), 0, stream>>>(
            ln2o + r0*DM, WinT, b_in, nullptr, hidden, nullptr, DMLP, DM);
        gemm_bt_thin<0,2,1><<<dim3(DM/64, 4096/128), dim3(256), 0, stream>>>(
            hidden, WoutT, b_out, (float*)d_out + r0*DM, (float*)d_out + r0*DM, DM, DMLP);
    }
}

// Round 9
// 439.966 us; speedup vs baseline: 1.0468x; 1.0015x over previous
//
#include <hip/hip_runtime.h>
#include <hip/hip_bf16.h>
#include <math.h>

#define DM 768
#define NH 12
#define DH 64
#define DMLP 3072
#define BATCH 8
#define SEQ 1024
#define NTOK (BATCH*SEQ)
#define QKVN (3*DM)
#define LN_EPS 1e-5f

typedef __hip_bfloat16 bf16;
typedef __attribute__((ext_vector_type(8))) short bf16x8;
typedef __attribute__((ext_vector_type(4))) float f32x4;

#define MFMA16(a,b,c) __builtin_amdgcn_mfma_f32_16x16x32_bf16((a),(b),(c),0,0,0)

__device__ __forceinline__ float us2f(unsigned short u){
    unsigned int i = ((unsigned int)u) << 16; float f; __builtin_memcpy(&f, &i, 4); return f;
}
__device__ __forceinline__ short f2bs(float f){
    bf16 h = __float2bfloat16(f); short s; __builtin_memcpy(&s, &h, 2); return s;
}

// gelu_new(x) = x * sigmoid(2c(x + 0.044715 x^3)), c = sqrt(2/pi). ~7 VALU ops.
__device__ __forceinline__ float gelu_f(float x){
    float y = 1.5957691216057308f*(x + 0.044715f*x*x*x);
    return x * __builtin_amdgcn_rcpf(1.0f + __expf(-y));
}

// LN-normalize 8 fp32 -> bf16x8: y = x*rw + (b + nmu*rw), rw = r*w, nmu = -mean
__device__ __forceinline__ bf16x8 norm_pack(f32x4 xl, f32x4 xh, f32x4 wl, f32x4 wh,
                                            f32x4 bl, f32x4 bh, float nmu, float r){
    bf16x8 o;
    #pragma unroll
    for (int i = 0; i < 4; i++){
        float rw = r*wl[i];
        o[i] = f2bs(xl[i]*rw + (bl[i] + nmu*rw));
    }
    #pragma unroll
    for (int i = 0; i < 4; i++){
        float rw = r*wh[i];
        o[4+i] = f2bs(xh[i]*rw + (bh[i] + nmu*rw));
    }
    return o;
}

// ---------------- transpose + fp32->bf16 convert: out[N][K] = in[K][N] ----------------
__global__ __launch_bounds__(256) void transpose_cvt(const float* __restrict__ in,
                                                     short* __restrict__ out,
                                                     int K, int N)
{
    __shared__ float t[32][33];
    int n0 = blockIdx.x*32, k0 = blockIdx.y*32;
    int tx = threadIdx.x & 31, ty = threadIdx.x >> 5;
    #pragma unroll
    for (int i = 0; i < 32; i += 8)
        t[ty+i][tx] = in[(size_t)(k0+ty+i)*N + n0+tx];
    __syncthreads();
    #pragma unroll
    for (int i = 0; i < 32; i += 8)
        out[(size_t)(n0+ty+i)*K + k0+tx] = f2bs(t[tx][ty+i]);
}

// qkv weights: W_{q,k,v}[h][k][e] -> wqkvT[n = which*768 + h*64 + e][k], bf16
__global__ __launch_bounds__(256) void transpose_cvt_qkv(const float* __restrict__ Wq,
                                                         const float* __restrict__ Wk,
                                                         const float* __restrict__ Wv,
                                                         short* __restrict__ out)
{
    __shared__ float t[32][33];
    int zz = blockIdx.z;
    int which = zz / 12, h = zz % 12;
    const float* in = (which == 0 ? Wq : which == 1 ? Wk : Wv) + (size_t)h*DM*DH;
    short* o = out + ((size_t)which*DM + h*DH)*DM;
    int n0 = blockIdx.x*32, k0 = blockIdx.y*32;
    int tx = threadIdx.x & 31, ty = threadIdx.x >> 5;
    #pragma unroll
    for (int i = 0; i < 32; i += 8)
        t[ty+i][tx] = in[(size_t)(k0+ty+i)*DH + n0+tx];
    __syncthreads();
    #pragma unroll
    for (int i = 0; i < 32; i += 8)
        o[(size_t)(n0+ty+i)*DM + k0+tx] = f2bs(t[tx][ty+i]);
}

// concat b_Q|b_K|b_V -> [2304] fp32
__global__ __launch_bounds__(256) void prep_qkv_bias(const float* bQ, const float* bK, const float* bV,
                                                     float* __restrict__ out)
{
    int idx = blockIdx.x*256 + threadIdx.x;
    if (idx >= QKVN) return;
    int which = idx / DM, hc = idx % DM;
    const float* b = (which == 0) ? bQ : ((which == 1) ? bK : bV);
    out[idx] = b[hc];
}

// v_rm [8192][768] bf16 -> vT [(b*12+h)*64 + d][1024] bf16
__global__ __launch_bounds__(256) void transpose_v(const short* __restrict__ v_rm,
                                                   short* __restrict__ vT)
{
    __shared__ short t[64][65];
    int st = blockIdx.x, h = blockIdx.y, b = blockIdx.z;
    int tok = threadIdx.x >> 2, seg = (threadIdx.x & 3)*16;
    const short* src = v_rm + (size_t)(b*SEQ + st*64 + tok)*DM + h*DH + seg;
    bf16x8 a0 = *(const bf16x8*)src;
    bf16x8 a1 = *(const bf16x8*)(src + 8);
    #pragma unroll
    for (int i = 0; i < 8; i++) t[seg + i][tok]     = a0[i];
    #pragma unroll
    for (int i = 0; i < 8; i++) t[seg + 8 + i][tok] = a1[i];
    __syncthreads();
    int d = threadIdx.x >> 2; int sk = (threadIdx.x & 3)*16;
    short* dst = vT + ((size_t)(b*NH + h)*DH + d)*SEQ + st*64 + sk;
    bf16x8 w0, w1;
    #pragma unroll
    for (int i = 0; i < 8; i++) w0[i] = t[d][sk + i];
    #pragma unroll
    for (int i = 0; i < 8; i++) w1[i] = t[d][sk + 8 + i];
    *(bf16x8*)dst = w0;
    *(bf16x8*)(dst + 8) = w1;
}

// ---------------- LN stats: per-row mean & rstd of fp32 [8192][768] ----------------
__device__ __forceinline__ float block_reduce_sum(float v, float* buf){
    int tid = threadIdx.x;
    buf[tid] = v; __syncthreads();
    for (int s = 128; s > 0; s >>= 1){
        if (tid < s) buf[tid] += buf[tid + s];
        __syncthreads();
    }
    float r = buf[0]; __syncthreads();
    return r;
}

__global__ __launch_bounds__(256) void ln_stats(const float* __restrict__ x,
                                                float2* __restrict__ st)
{
    __shared__ float buf[256];
    int row = blockIdx.x, tid = threadIdx.x;
    const float* xr = x + (size_t)row*DM;
    float s = 0.f, s2 = 0.f;
    #pragma unroll
    for (int i = 0; i < 3; i++){
        float t = xr[tid + 256*i];
        s += t; s2 += t*t;
    }
    float sum  = block_reduce_sum(s,  buf);
    float sum2 = block_reduce_sum(s2, buf);
    if (tid == 0){
        float mean = sum * (1.0f/DM);
        float var  = sum2 * (1.0f/DM) - mean*mean;
        st[row] = make_float2(mean, rsqrtf(var + LN_EPS));
    }
}

// Swizzle (BK=32, 64B rows): data(row m, seg s) stored at seg c = s ^ ((m>>1)&3).
// Staging lane l -> row r4=l>>2, stored seg l&3, global seg (l&3)^((r4>>1)&3).
// Frag read covers all 8 bank-groups (r7/r8-verified: 0 conflicts).

// ---------------- MFMA B^T GEMM, 128x128 tile, BK=32, register-staged dbuf -------------
// AFP32=1: A is raw fp32 + per-row LN stats + lnw/lnb fused into staging (normalize at
// the ds_write commit point, after the MFMAs, so global latency stays overlapped).
// EPI: 1=gelu. RES: 2=fp32 residual. OUT: 0 bf16, 1 fp32.
// SPLITV: cols<1536 -> Cp (stride 1536), cols>=1536 -> Cp2 (stride 768), both bf16.
template<int EPI, int RES, int OUT, int SPLITV, int AFP32>
__global__ __launch_bounds__(256) void gemm_bt(const void* __restrict__ Ap_,
                                               const short* __restrict__ Bt,
                                               const float* __restrict__ bias,
                                               const void* __restrict__ resp,
                                               const float2* __restrict__ stats,
                                               const float* __restrict__ lnw,
                                               const float* __restrict__ lnb,
                                               void* __restrict__ Cp,
                                               void* __restrict__ Cp2,
                                               int N, int K)
{
    __shared__ alignas(16) short As[2][128*32];
    __shared__ alignas(16) short Bs[2][128*32];
    int tid = threadIdx.x, lane = tid & 63, w = tid >> 6;
    int l15 = lane & 15, quad = lane >> 4;
    int m_base = blockIdx.y*128, n_base = blockIdx.x*128;

    int r4 = lane >> 2;
    int sG = ((lane & 3) ^ ((r4 >> 1) & 3)) * 8;
    int rowA0 = m_base + 32*w + r4, rowA1 = rowA0 + 16;
    const short* gB0 = Bt + (size_t)(n_base + 32*w      + r4)*K + sG;
    const short* gB1 = Bt + (size_t)(n_base + 32*w + 16 + r4)*K + sG;
    int la0 = (2*w)*512 + lane*8, la1 = (2*w+1)*512 + lane*8;

    const short* gA0b = nullptr; const short* gA1b = nullptr;
    const float* gA0f = nullptr; const float* gA1f = nullptr;
    float nmu0 = 0.f, rr0 = 0.f, nmu1 = 0.f, rr1 = 0.f;
    if (AFP32){
        gA0f = (const float*)Ap_ + (size_t)rowA0*K + sG;
        gA1f = (const float*)Ap_ + (size_t)rowA1*K + sG;
        float2 s0 = stats[rowA0], s1 = stats[rowA1];
        nmu0 = -s0.x; rr0 = s0.y; nmu1 = -s1.x; rr1 = s1.y;
    } else {
        gA0b = (const short*)Ap_ + (size_t)rowA0*K + sG;
        gA1b = (const short*)Ap_ + (size_t)rowA1*K + sG;
    }

    int mrow0 = (w >> 1)*64, ncol0 = (w & 1)*64;
    f32x4 acc[4][4] = {};

    // prologue: stage k-chunk 0 into buf 0
    if (AFP32){
        f32x4 x0l = *(const f32x4*)gA0f, x0h = *(const f32x4*)(gA0f + 4);
        f32x4 x1l = *(const f32x4*)gA1f, x1h = *(const f32x4*)(gA1f + 4);
        f32x4 wl = *(const f32x4*)(lnw + sG), wh = *(const f32x4*)(lnw + sG + 4);
        f32x4 bl = *(const f32x4*)(lnb + sG), bh = *(const f32x4*)(lnb + sG + 4);
        *(bf16x8*)&As[0][la0] = norm_pack(x0l, x0h, wl, wh, bl, bh, nmu0, rr0);
        *(bf16x8*)&As[0][la1] = norm_pack(x1l, x1h, wl, wh, bl, bh, nmu1, rr1);
    } else {
        *(bf16x8*)&As[0][la0] = *(const bf16x8*)gA0b;
        *(bf16x8*)&As[0][la1] = *(const bf16x8*)gA1b;
    }
    *(bf16x8*)&Bs[0][la0] = *(const bf16x8*)gB0;
    *(bf16x8*)&Bs[0][la1] = *(const bf16x8*)gB1;
    __syncthreads();

    bf16x8 pa0, pa1, pb0, pb1;
    f32x4 xa0l, xa0h, xa1l, xa1h, pwl, pwh, pbl, pbh;
    int nk = K >> 5;
    for (int ki = 0; ki < nk; ki++){
        int cur = ki & 1, nxt = cur ^ 1;
        if (ki + 1 < nk){
            int off = (ki + 1) << 5;
            if (AFP32){
                xa0l = *(const f32x4*)(gA0f + off); xa0h = *(const f32x4*)(gA0f + off + 4);
                xa1l = *(const f32x4*)(gA1f + off); xa1h = *(const f32x4*)(gA1f + off + 4);
                pwl = *(const f32x4*)(lnw + off + sG); pwh = *(const f32x4*)(lnw + off + sG + 4);
                pbl = *(const f32x4*)(lnb + off + sG); pbh = *(const f32x4*)(lnb + off + sG + 4);
            } else {
                pa0 = *(const bf16x8*)(gA0b + off); pa1 = *(const bf16x8*)(gA1b + off);
            }
            pb0 = *(const bf16x8*)(gB0 + off); pb1 = *(const bf16x8*)(gB1 + off);
        }
        bf16x8 af[4], bfr[4];
        #pragma unroll
        for (int i = 0; i < 4; i++){
            int m = mrow0 + 16*i + l15;
            af[i] = *(const bf16x8*)(&As[cur][m*32 + ((quad ^ ((m >> 1) & 3))*8)]);
        }
        #pragma unroll
        for (int j = 0; j < 4; j++){
            int n = ncol0 + 16*j + l15;
            bfr[j] = *(const bf16x8*)(&Bs[cur][n*32 + ((quad ^ ((n >> 1) & 3))*8)]);
        }
        #pragma unroll
        for (int i = 0; i < 4; i++)
            #pragma unroll
            for (int j = 0; j < 4; j++)
                acc[i][j] = MFMA16(af[i], bfr[j], acc[i][j]);
        if (ki + 1 < nk){
            if (AFP32){
                *(bf16x8*)&As[nxt][la0] = norm_pack(xa0l, xa0h, pwl, pwh, pbl, pbh, nmu0, rr0);
                *(bf16x8*)&As[nxt][la1] = norm_pack(xa1l, xa1h, pwl, pwh, pbl, pbh, nmu1, rr1);
            } else {
                *(bf16x8*)&As[nxt][la0] = pa0; *(bf16x8*)&As[nxt][la1] = pa1;
            }
            *(bf16x8*)&Bs[nxt][la0] = pb0; *(bf16x8*)&Bs[nxt][la1] = pb1;
        }
        __syncthreads();
    }

    #pragma unroll
    for (int i = 0; i < 4; i++){
        #pragma unroll
        for (int j = 0; j < 4; j++){
            #pragma unroll
            for (int r = 0; r < 4; r++){
                size_t row = (size_t)(m_base + mrow0 + 16*i + quad*4 + r);
                int    col = n_base + ncol0 + 16*j + l15;
                float v = acc[i][j][r] + bias[col];
                if (EPI == 1) v = gelu_f(v);
                if (RES == 2) v += ((const float*)resp)[row*N + col];
                if (SPLITV){
                    if (col < 1536) ((short*)Cp )[row*1536 + col]        = f2bs(v);
                    else            ((short*)Cp2)[row*768  + col - 1536] = f2bs(v);
                } else if (OUT == 0) ((short*)Cp)[row*N + col] = f2bs(v);
                else                 ((float*)Cp)[row*N + col] = v;
            }
        }
    }
}

// ---------------- thin MFMA GEMM: 128x64 tile, BK=32, register-staged dbuf --------------
template<int EPI, int RES, int OUT>
__global__ __launch_bounds__(256) void gemm_bt_thin(const short* __restrict__ A,
                                                    const short* __restrict__ Bt,
                                                    const float* __restrict__ bias,
                                                    const void* __restrict__ resp,
                                                    void* __restrict__ Cp,
                                                    int N, int K)
{
    __shared__ alignas(16) short As[2][128*32];
    __shared__ alignas(16) short Bs[2][64*32];
    int tid = threadIdx.x, lane = tid & 63, w = tid >> 6;
    int l15 = lane & 15, quad = lane >> 4;
    int m_base = blockIdx.y*128, n_base = blockIdx.x*64;

    int r4 = lane >> 2;
    int sG = ((lane & 3) ^ ((r4 >> 1) & 3)) * 8;
    const short* gA0 = A  + (size_t)(m_base + 32*w      + r4)*K + sG;
    const short* gA1 = A  + (size_t)(m_base + 32*w + 16 + r4)*K + sG;
    const short* gB0 = Bt + (size_t)(n_base + 16*w      + r4)*K + sG;
    int la0 = (2*w)*512 + lane*8, la1 = (2*w+1)*512 + lane*8;
    int lb0 = w*512 + lane*8;

    f32x4 acc[2][4] = {};

    bf16x8 pa0 = *(const bf16x8*)gA0, pa1 = *(const bf16x8*)gA1;
    bf16x8 pb0 = *(const bf16x8*)gB0;
    *(bf16x8*)&As[0][la0] = pa0; *(bf16x8*)&As[0][la1] = pa1;
    *(bf16x8*)&Bs[0][lb0] = pb0;
    __syncthreads();

    int nk = K >> 5;
    for (int ki = 0; ki < nk; ki++){
        int cur = ki & 1, nxt = cur ^ 1;
        if (ki + 1 < nk){
            int off = (ki + 1) << 5;
            pa0 = *(const bf16x8*)(gA0 + off); pa1 = *(const bf16x8*)(gA1 + off);
            pb0 = *(const bf16x8*)(gB0 + off);
        }
        bf16x8 af[2], bfr[4];
        #pragma unroll
        for (int i = 0; i < 2; i++){
            int m = 32*w + 16*i + l15;
            af[i] = *(const bf16x8*)(&As[cur][m*32 + ((quad ^ ((m >> 1) & 3))*8)]);
        }
        #pragma unroll
        for (int j = 0; j < 4; j++){
            int n = 16*j + l15;
            bfr[j] = *(const bf16x8*)(&Bs[cur][n*32 + ((quad ^ ((n >> 1) & 3))*8)]);
        }
        #pragma unroll
        for (int i = 0; i < 2; i++)
            #pragma unroll
            for (int j = 0; j < 4; j++)
                acc[i][j] = MFMA16(af[i], bfr[j], acc[i][j]);
        if (ki + 1 < nk){
            *(bf16x8*)&As[nxt][la0] = pa0; *(bf16x8*)&As[nxt][la1] = pa1;
            *(bf16x8*)&Bs[nxt][lb0] = pb0;
        }
        __syncthreads();
    }

    #pragma unroll
    for (int i = 0; i < 2; i++){
        #pragma unroll
        for (int j = 0; j < 4; j++){
            #pragma unroll
            for (int r = 0; r < 4; r++){
                size_t row = (size_t)(m_base + 32*w + 16*i + quad*4 + r);
                int    col = n_base + 16*j + l15;
                float v = acc[i][j][r] + bias[col];
                if (EPI == 1) v = gelu_f(v);
                if (RES == 2) v += ((const float*)resp)[row*N + col];
                if (OUT == 0) ((short*)Cp)[row*N + col] = f2bs(v);
                else          ((float*)Cp)[row*N + col] = v;
            }
        }
    }
}

// ---------------- MFMA flash attention: register-staged K/V dbuf, paired q-tiles -------
__global__ __launch_bounds__(256) void flash_attn(const short* __restrict__ qk,
                                                  const short* __restrict__ vT,
                                                  short* __restrict__ z)
{
    __shared__ alignas(16) short U[4608];        // Q tile [64][64] swz / Ps [4][16][72]
    __shared__ alignas(16) short Ks[2][64*64];
    __shared__ alignas(16) short Vt[2][64*64];
    int p = blockIdx.x, h = blockIdx.y, b = blockIdx.z;
    int tid = threadIdx.x, lane = tid & 63, w = tid >> 6;
    int l15 = lane & 15, quad = lane >> 4;
    int r8 = lane >> 3, u8 = lane & 7;
    int useg = (u8 ^ r8) * 8;
    int lc0 = (2*w)*512 + lane*8, lc1 = (2*w+1)*512 + lane*8;

    const short* kbase = qk + DM + h*DH;
    const short* vbase = vT + (size_t)(b*NH + h)*DH*SEQ;

    for (int phase = 0; phase < 2; phase++){
        int qt = phase ? (15 - p) : p;

        __syncthreads();
        {
            bf16x8 q0 = *(const bf16x8*)(qk + (size_t)(b*SEQ + qt*64 + 16*w + r8)*1536 + h*DH + useg);
            bf16x8 q1 = *(const bf16x8*)(qk + (size_t)(b*SEQ + qt*64 + 16*w + 8 + r8)*1536 + h*DH + useg);
            bf16x8 k0 = *(const bf16x8*)(kbase + (size_t)(b*SEQ + 16*w + r8)*1536 + useg);
            bf16x8 k1 = *(const bf16x8*)(kbase + (size_t)(b*SEQ + 16*w + 8 + r8)*1536 + useg);
            bf16x8 v0 = *(const bf16x8*)(vbase + (size_t)(16*w + r8)*SEQ + useg);
            bf16x8 v1 = *(const bf16x8*)(vbase + (size_t)(16*w + 8 + r8)*SEQ + useg);
            *(bf16x8*)&U[lc0] = q0;        *(bf16x8*)&U[lc1] = q1;
            *(bf16x8*)&Ks[0][lc0] = k0;    *(bf16x8*)&Ks[0][lc1] = k1;
            *(bf16x8*)&Vt[0][lc0] = v0;    *(bf16x8*)&Vt[0][lc1] = v1;
        }
        __syncthreads();

        bf16x8 aq[2];
        #pragma unroll
        for (int kk = 0; kk < 2; kk++)
            aq[kk] = *(const bf16x8*)(U + (16*w + l15)*64 + (((4*kk + quad) ^ (l15 & 7))*8));

        float m_state[4] = {-1e30f,-1e30f,-1e30f,-1e30f};
        float l_state[4] = {0.f,0.f,0.f,0.f};
        f32x4 o_acc[4] = {};
        int rg = qt*64 + w*16 + quad*4;

        for (int kt = 0; kt <= qt; ++kt){
            int cur = kt & 1, nxt = cur ^ 1;
            bf16x8 pk0, pk1, pv0, pv1;
            if (kt < qt){
                pk0 = *(const bf16x8*)(kbase + (size_t)(b*SEQ + (kt+1)*64 + 16*w + r8)*1536 + useg);
                pk1 = *(const bf16x8*)(kbase + (size_t)(b*SEQ + (kt+1)*64 + 16*w + 8 + r8)*1536 + useg);
                pv0 = *(const bf16x8*)(vbase + (size_t)(16*w + r8)*SEQ + (kt+1)*64 + useg);
                pv1 = *(const bf16x8*)(vbase + (size_t)(16*w + 8 + r8)*SEQ + (kt+1)*64 + useg);
            }

            f32x4 s[4] = {};
            #pragma unroll
            for (int kk = 0; kk < 2; kk++){
                int swz = ((4*kk + quad) ^ (l15 & 7)) * 8;
                #pragma unroll
                for (int j = 0; j < 4; j++){
                    bf16x8 bk = *(const bf16x8*)(&Ks[cur][(16*j + l15)*64 + swz]);
                    s[j] = MFMA16(aq[kk], bk, s[j]);
                }
            }

            bool diag = (kt == qt);
            #pragma unroll
            for (int j = 0; j < 4; j++){
                int col_g = kt*64 + 16*j + l15;
                #pragma unroll
                for (int r = 0; r < 4; r++){
                    float v = s[j][r] * 0.125f;
                    if (diag && col_g > rg + r) v = -1e30f;
                    s[j][r] = v;
                }
            }

            #pragma unroll
            for (int r = 0; r < 4; r++){
                float mx = fmaxf(fmaxf(s[0][r], s[1][r]), fmaxf(s[2][r], s[3][r]));
                #pragma unroll
                for (int d = 1; d < 16; d <<= 1) mx = fmaxf(mx, __shfl_xor(mx, d, 64));
                float m_new = fmaxf(m_state[r], mx);
                float alpha = __expf(m_state[r] - m_new);
                m_state[r] = m_new;
                float rs = 0.f;
                #pragma unroll
                for (int j = 0; j < 4; j++){
                    float pv = __expf(s[j][r] - m_new);
                    s[j][r] = pv; rs += pv;
                }
                #pragma unroll
                for (int d = 1; d < 16; d <<= 1) rs += __shfl_xor(rs, d, 64);
                l_state[r] = l_state[r]*alpha + rs;
                #pragma unroll
                for (int j = 0; j < 4; j++) o_acc[j][r] *= alpha;
            }

            #pragma unroll
            for (int j = 0; j < 4; j++)
                #pragma unroll
                for (int r = 0; r < 4; r++)
                    U[w*1152 + (quad*4 + r)*72 + 16*j + l15] = f2bs(s[j][r]);

            #pragma unroll
            for (int kk = 0; kk < 2; kk++){
                bf16x8 ap = *(const bf16x8*)(U + w*1152 + l15*72 + 32*kk + quad*8);
                int swz = ((4*kk + quad) ^ (l15 & 7)) * 8;
                #pragma unroll
                for (int j = 0; j < 4; j++){
                    bf16x8 bv = *(const bf16x8*)(&Vt[cur][(16*j + l15)*64 + swz]);
                    o_acc[j] = MFMA16(ap, bv, o_acc[j]);
                }
            }

            if (kt < qt){
                *(bf16x8*)&Ks[nxt][lc0] = pk0;  *(bf16x8*)&Ks[nxt][lc1] = pk1;
                *(bf16x8*)&Vt[nxt][lc0] = pv0;  *(bf16x8*)&Vt[nxt][lc1] = pv1;
            }
            __syncthreads();
        }

        #pragma unroll
        for (int r = 0; r < 4; r++){
            float inv_l = 1.0f / l_state[r];
            size_t row = (size_t)(b*SEQ + rg + r);
            #pragma unroll
            for (int j = 0; j < 4; j++)
                z[row*DM + h*DH + 16*j + l15] = f2bs(o_acc[j][r] * inv_l);
        }
    }
}

// ---------------- launch ----------------
// ws map (59,909,120 B, lifetime-aliased; fused-LN dataflow):
//   A0 [0, 3538944)          wqkvT  -> WinT (A0+A1) after O-gemm
//   A1 [3538944, 4718592)    WOT
//   A2 [4718592, 4727808)    bias_qkv fp32
//   A3 [4727808, 29893632)   qk bf16 [qkv-gemm -> flash]  }
//   A4 [29893632, 42476544)  v_rm -> zbuf [flash -> O]    } hidden bf16 50,331,648 B
//   A5 [42476544, 55059456)  vT [transpose_v -> flash]    }   [MLP-in -> MLP-out]
//   A6 [55059456, 59778048)  WoutT
//   stats1 @ 59778048 (64KB), stats2 @ 59843584 (64KB)
// resid_mid lives in d_out (fp32): O-gemm writes it, MLP reads it via fused LN + residual.
extern "C" void kernel_launch(void* const* d_in, const int* in_sizes, int n_in,
                              void* d_out, int out_size, void* d_ws, size_t ws_size,
                              hipStream_t stream)
{
    const float* resid_pre = (const float*)d_in[0];
    const float* W_Q  = (const float*)d_in[1];
    const float* W_K  = (const float*)d_in[2];
    const float* W_V  = (const float*)d_in[3];
    const float* W_O  = (const float*)d_in[4];
    const float* b_Q  = (const float*)d_in[5];
    const float* b_K  = (const float*)d_in[6];
    const float* b_V  = (const float*)d_in[7];
    const float* b_O  = (const float*)d_in[8];
    const float* ln1w = (const float*)d_in[9];
    const float* ln1b = (const float*)d_in[10];
    const float* ln2w = (const float*)d_in[11];
    const float* ln2b = (const float*)d_in[12];
    const float* W_in = (const float*)d_in[13];
    const float* b_in = (const float*)d_in[14];
    const float* W_out= (const float*)d_in[15];
    const float* b_out= (const float*)d_in[16];

    char* ws = (char*)d_ws;
    short*  wqkvT    = (short*)(ws);
    short*  WOT      = (short*)(ws + 3538944);
    float*  bias_qkv = (float*)(ws + 4718592);
    short*  WinT     = (short*)(ws);             // after O-gemm
    short*  qk       = (short*)(ws + 4727808);   // A3
    short*  hidden   = (short*)(ws + 4727808);   // A3+A4+A5 after flash/O-gemm
    short*  v_rm     = (short*)(ws + 29893632);  // A4
    short*  zbuf     = (short*)(ws + 29893632);  // A4 after transpose_v
    short*  vT       = (short*)(ws + 42476544);  // A5
    short*  WoutT    = (short*)(ws + 55059456);  // A6
    float2* stats1   = (float2*)(ws + 59778048);
    float2* stats2   = (float2*)(ws + 59843584);

    // prep
    transpose_cvt_qkv<<<dim3(2, 24, 36), dim3(256), 0, stream>>>(W_Q, W_K, W_V, wqkvT);
    prep_qkv_bias<<<dim3(9), dim3(256), 0, stream>>>(b_Q, b_K, b_V, bias_qkv);
    transpose_cvt<<<dim3(24, 24), dim3(256), 0, stream>>>(W_O,   WOT,   DM,   DM);
    transpose_cvt<<<dim3(24, 96), dim3(256), 0, stream>>>(W_out, WoutT, DMLP, DM);

    // ln1 stats + QKV projection w/ fused LN (split: Q,K -> qk, V -> v_rm)
    ln_stats<<<dim3(NTOK), dim3(256), 0, stream>>>(resid_pre, stats1);
    gemm_bt<0,0,0,1,1><<<dim3(QKVN/128, NTOK/128), dim3(256), 0, stream>>>(
        resid_pre, wqkvT, bias_qkv, nullptr, stats1, ln1w, ln1b, qk, v_rm, QKVN, DM);

    // V transpose then flash attention
    transpose_v<<<dim3(SEQ/64, NH, BATCH), dim3(256), 0, stream>>>(v_rm, vT);
    flash_attn<<<dim3(SEQ/128, NH, BATCH), dim3(256), 0, stream>>>(qk, vT, zbuf);

    // O projection + residual(resid_pre fp32) -> d_out fp32
    gemm_bt_thin<0,2,1><<<dim3(DM/64, NTOK/128), dim3(256), 0, stream>>>(
        zbuf, WOT, b_O, resid_pre, d_out, DM, DM);

    // W_in transpose (A0/A1 dead)
    transpose_cvt<<<dim3(96, 24), dim3(256), 0, stream>>>(W_in, WinT, DM, DMLP);

    // ln2 stats on d_out (fp32)
    ln_stats<<<dim3(NTOK), dim3(256), 0, stream>>>((const float*)d_out, stats2);

    // MLP single-pass: in (fused LN + gelu) -> hidden; out (+residual, in-place d_out)
    gemm_bt<1,0,0,0,1><<<dim3(DMLP/128, NTOK/128), dim3(256), 0, stream>>>(
        d_out, WinT, b_in, nullptr, stats2, ln2w, ln2b, hidden, nullptr, DMLP, DM);
    gemm_bt_thin<0,2,1><<<dim3(DM/64, NTOK/128), dim3(256), 0, stream>>>(
        hidden, WoutT, b_out, d_out, d_out, DM, DMLP);
}

// Round 10
// 415.625 us; speedup vs baseline: 1.1081x; 1.0586x over previous
//
#include <hip/hip_runtime.h>
#include <hip/hip_bf16.h>
#include <math.h>

#define DM 768
#define NH 12
#define DH 64
#define DMLP 3072
#define BATCH 8
#define SEQ 1024
#define NTOK (BATCH*SEQ)
#define QKVN (3*DM)
#define LN_EPS 1e-5f

typedef __hip_bfloat16 bf16;
typedef __attribute__((ext_vector_type(8))) short bf16x8;
typedef __attribute__((ext_vector_type(4))) float f32x4;

#define MFMA16(a,b,c) __builtin_amdgcn_mfma_f32_16x16x32_bf16((a),(b),(c),0,0,0)

__device__ __forceinline__ float us2f(unsigned short u){
    unsigned int i = ((unsigned int)u) << 16; float f; __builtin_memcpy(&f, &i, 4); return f;
}
__device__ __forceinline__ short f2bs(float f){
    bf16 h = __float2bfloat16(f); short s; __builtin_memcpy(&s, &h, 2); return s;
}

// gelu_new(x) = x * sigmoid(2c(x + 0.044715 x^3)), c = sqrt(2/pi). ~7 VALU ops.
__device__ __forceinline__ float gelu_f(float x){
    float y = 1.5957691216057308f*(x + 0.044715f*x*x*x);
    return x * __builtin_amdgcn_rcpf(1.0f + __expf(-y));
}

// XCD-aware block decode: 1D grid, xcd = bid&7 (HW round-robin heuristic).
// Each XCD owns (gridDim/8)/NXB contiguous row-bands x all NXB n-tiles, so the
// A row-band (and B tiles) stay resident in that XCD's private L2.
__device__ __forceinline__ void xcd_map(int NXB, int& bx, int& by){
    int bid = blockIdx.x;
    int xcd = bid & 7, slot = bid >> 3;
    int bands = (gridDim.x >> 3) / NXB;
    by = xcd * bands + slot / NXB;
    bx = slot % NXB;
}

// LN-normalize 8 fp32 -> bf16x8: y = x*rw + (b + nmu*rw), rw = r*w, nmu = -mean
__device__ __forceinline__ bf16x8 norm_pack(f32x4 xl, f32x4 xh, f32x4 wl, f32x4 wh,
                                            f32x4 bl, f32x4 bh, float nmu, float r){
    bf16x8 o;
    #pragma unroll
    for (int i = 0; i < 4; i++){
        float rw = r*wl[i];
        o[i] = f2bs(xl[i]*rw + (bl[i] + nmu*rw));
    }
    #pragma unroll
    for (int i = 0; i < 4; i++){
        float rw = r*wh[i];
        o[4+i] = f2bs(xh[i]*rw + (bh[i] + nmu*rw));
    }
    return o;
}

// ---------------- transpose + fp32->bf16 convert: out[N][K] = in[K][N] ----------------
__global__ __launch_bounds__(256) void transpose_cvt(const float* __restrict__ in,
                                                     short* __restrict__ out,
                                                     int K, int N)
{
    __shared__ float t[32][33];
    int n0 = blockIdx.x*32, k0 = blockIdx.y*32;
    int tx = threadIdx.x & 31, ty = threadIdx.x >> 5;
    #pragma unroll
    for (int i = 0; i < 32; i += 8)
        t[ty+i][tx] = in[(size_t)(k0+ty+i)*N + n0+tx];
    __syncthreads();
    #pragma unroll
    for (int i = 0; i < 32; i += 8)
        out[(size_t)(n0+ty+i)*K + k0+tx] = f2bs(t[tx][ty+i]);
}

// qkv weights: W_{q,k,v}[h][k][e] -> wqkvT[n = which*768 + h*64 + e][k], bf16
__global__ __launch_bounds__(256) void transpose_cvt_qkv(const float* __restrict__ Wq,
                                                         const float* __restrict__ Wk,
                                                         const float* __restrict__ Wv,
                                                         short* __restrict__ out)
{
    __shared__ float t[32][33];
    int zz = blockIdx.z;
    int which = zz / 12, h = zz % 12;
    const float* in = (which == 0 ? Wq : which == 1 ? Wk : Wv) + (size_t)h*DM*DH;
    short* o = out + ((size_t)which*DM + h*DH)*DM;
    int n0 = blockIdx.x*32, k0 = blockIdx.y*32;
    int tx = threadIdx.x & 31, ty = threadIdx.x >> 5;
    #pragma unroll
    for (int i = 0; i < 32; i += 8)
        t[ty+i][tx] = in[(size_t)(k0+ty+i)*DH + n0+tx];
    __syncthreads();
    #pragma unroll
    for (int i = 0; i < 32; i += 8)
        o[(size_t)(n0+ty+i)*DM + k0+tx] = f2bs(t[tx][ty+i]);
}

// concat b_Q|b_K|b_V -> [2304] fp32
__global__ __launch_bounds__(256) void prep_qkv_bias(const float* bQ, const float* bK, const float* bV,
                                                     float* __restrict__ out)
{
    int idx = blockIdx.x*256 + threadIdx.x;
    if (idx >= QKVN) return;
    int which = idx / DM, hc = idx % DM;
    const float* b = (which == 0) ? bQ : ((which == 1) ? bK : bV);
    out[idx] = b[hc];
}

// v_rm [8192][768] bf16 -> vT [(b*12+h)*64 + d][1024] bf16
__global__ __launch_bounds__(256) void transpose_v(const short* __restrict__ v_rm,
                                                   short* __restrict__ vT)
{
    __shared__ short t[64][65];
    int st = blockIdx.x, h = blockIdx.y, b = blockIdx.z;
    int tok = threadIdx.x >> 2, seg = (threadIdx.x & 3)*16;
    const short* src = v_rm + (size_t)(b*SEQ + st*64 + tok)*DM + h*DH + seg;
    bf16x8 a0 = *(const bf16x8*)src;
    bf16x8 a1 = *(const bf16x8*)(src + 8);
    #pragma unroll
    for (int i = 0; i < 8; i++) t[seg + i][tok]     = a0[i];
    #pragma unroll
    for (int i = 0; i < 8; i++) t[seg + 8 + i][tok] = a1[i];
    __syncthreads();
    int d = threadIdx.x >> 2; int sk = (threadIdx.x & 3)*16;
    short* dst = vT + ((size_t)(b*NH + h)*DH + d)*SEQ + st*64 + sk;
    bf16x8 w0, w1;
    #pragma unroll
    for (int i = 0; i < 8; i++) w0[i] = t[d][sk + i];
    #pragma unroll
    for (int i = 0; i < 8; i++) w1[i] = t[d][sk + 8 + i];
    *(bf16x8*)dst = w0;
    *(bf16x8*)(dst + 8) = w1;
}

// ---------------- LN stats: per-row mean & rstd of fp32 [8192][768] ----------------
__device__ __forceinline__ float block_reduce_sum(float v, float* buf){
    int tid = threadIdx.x;
    buf[tid] = v; __syncthreads();
    for (int s = 128; s > 0; s >>= 1){
        if (tid < s) buf[tid] += buf[tid + s];
        __syncthreads();
    }
    float r = buf[0]; __syncthreads();
    return r;
}

__global__ __launch_bounds__(256) void ln_stats(const float* __restrict__ x,
                                                float2* __restrict__ st)
{
    __shared__ float buf[256];
    int row = blockIdx.x, tid = threadIdx.x;
    const float* xr = x + (size_t)row*DM;
    float s = 0.f, s2 = 0.f;
    #pragma unroll
    for (int i = 0; i < 3; i++){
        float t = xr[tid + 256*i];
        s += t; s2 += t*t;
    }
    float sum  = block_reduce_sum(s,  buf);
    float sum2 = block_reduce_sum(s2, buf);
    if (tid == 0){
        float mean = sum * (1.0f/DM);
        float var  = sum2 * (1.0f/DM) - mean*mean;
        st[row] = make_float2(mean, rsqrtf(var + LN_EPS));
    }
}

// Swizzle (BK=32, 64B rows): data(row m, seg s) stored at seg c = s ^ ((m>>1)&3).
// Staging lane l -> row r4=l>>2, stored seg l&3, global seg (l&3)^((r4>>1)&3).
// Frag read covers all 8 bank-groups (r7/r8-verified: 0 conflicts).

// ---------------- MFMA B^T GEMM, 128x128 tile, BK=32, register-staged dbuf -------------
// 1D grid + XCD swizzle (NXB n-tiles). AFP32=1: fused LN on fp32 A during staging.
// EPI: 1=gelu. RES: 2=fp32 residual. OUT: 0 bf16, 1 fp32.
// SPLITV: cols<1536 -> Cp (stride 1536), cols>=1536 -> Cp2 (stride 768), both bf16.
template<int EPI, int RES, int OUT, int SPLITV, int AFP32>
__global__ __launch_bounds__(256) void gemm_bt(const void* __restrict__ Ap_,
                                               const short* __restrict__ Bt,
                                               const float* __restrict__ bias,
                                               const void* __restrict__ resp,
                                               const float2* __restrict__ stats,
                                               const float* __restrict__ lnw,
                                               const float* __restrict__ lnb,
                                               void* __restrict__ Cp,
                                               void* __restrict__ Cp2,
                                               int N, int K, int NXB)
{
    __shared__ alignas(16) short As[2][128*32];
    __shared__ alignas(16) short Bs[2][128*32];
    int tid = threadIdx.x, lane = tid & 63, w = tid >> 6;
    int l15 = lane & 15, quad = lane >> 4;
    int bx, by; xcd_map(NXB, bx, by);
    int m_base = by*128, n_base = bx*128;

    int r4 = lane >> 2;
    int sG = ((lane & 3) ^ ((r4 >> 1) & 3)) * 8;
    int rowA0 = m_base + 32*w + r4, rowA1 = rowA0 + 16;
    const short* gB0 = Bt + (size_t)(n_base + 32*w      + r4)*K + sG;
    const short* gB1 = Bt + (size_t)(n_base + 32*w + 16 + r4)*K + sG;
    int la0 = (2*w)*512 + lane*8, la1 = (2*w+1)*512 + lane*8;

    const short* gA0b = nullptr; const short* gA1b = nullptr;
    const float* gA0f = nullptr; const float* gA1f = nullptr;
    float nmu0 = 0.f, rr0 = 0.f, nmu1 = 0.f, rr1 = 0.f;
    if (AFP32){
        gA0f = (const float*)Ap_ + (size_t)rowA0*K + sG;
        gA1f = (const float*)Ap_ + (size_t)rowA1*K + sG;
        float2 s0 = stats[rowA0], s1 = stats[rowA1];
        nmu0 = -s0.x; rr0 = s0.y; nmu1 = -s1.x; rr1 = s1.y;
    } else {
        gA0b = (const short*)Ap_ + (size_t)rowA0*K + sG;
        gA1b = (const short*)Ap_ + (size_t)rowA1*K + sG;
    }

    int mrow0 = (w >> 1)*64, ncol0 = (w & 1)*64;
    f32x4 acc[4][4] = {};

    if (AFP32){
        f32x4 x0l = *(const f32x4*)gA0f, x0h = *(const f32x4*)(gA0f + 4);
        f32x4 x1l = *(const f32x4*)gA1f, x1h = *(const f32x4*)(gA1f + 4);
        f32x4 wl = *(const f32x4*)(lnw + sG), wh = *(const f32x4*)(lnw + sG + 4);
        f32x4 bl = *(const f32x4*)(lnb + sG), bh = *(const f32x4*)(lnb + sG + 4);
        *(bf16x8*)&As[0][la0] = norm_pack(x0l, x0h, wl, wh, bl, bh, nmu0, rr0);
        *(bf16x8*)&As[0][la1] = norm_pack(x1l, x1h, wl, wh, bl, bh, nmu1, rr1);
    } else {
        *(bf16x8*)&As[0][la0] = *(const bf16x8*)gA0b;
        *(bf16x8*)&As[0][la1] = *(const bf16x8*)gA1b;
    }
    *(bf16x8*)&Bs[0][la0] = *(const bf16x8*)gB0;
    *(bf16x8*)&Bs[0][la1] = *(const bf16x8*)gB1;
    __syncthreads();

    bf16x8 pa0, pa1, pb0, pb1;
    f32x4 xa0l, xa0h, xa1l, xa1h, pwl, pwh, pbl, pbh;
    int nk = K >> 5;
    for (int ki = 0; ki < nk; ki++){
        int cur = ki & 1, nxt = cur ^ 1;
        if (ki + 1 < nk){
            int off = (ki + 1) << 5;
            if (AFP32){
                xa0l = *(const f32x4*)(gA0f + off); xa0h = *(const f32x4*)(gA0f + off + 4);
                xa1l = *(const f32x4*)(gA1f + off); xa1h = *(const f32x4*)(gA1f + off + 4);
                pwl = *(const f32x4*)(lnw + off + sG); pwh = *(const f32x4*)(lnw + off + sG + 4);
                pbl = *(const f32x4*)(lnb + off + sG); pbh = *(const f32x4*)(lnb + off + sG + 4);
            } else {
                pa0 = *(const bf16x8*)(gA0b + off); pa1 = *(const bf16x8*)(gA1b + off);
            }
            pb0 = *(const bf16x8*)(gB0 + off); pb1 = *(const bf16x8*)(gB1 + off);
        }
        bf16x8 af[4], bfr[4];
        #pragma unroll
        for (int i = 0; i < 4; i++){
            int m = mrow0 + 16*i + l15;
            af[i] = *(const bf16x8*)(&As[cur][m*32 + ((quad ^ ((m >> 1) & 3))*8)]);
        }
        #pragma unroll
        for (int j = 0; j < 4; j++){
            int n = ncol0 + 16*j + l15;
            bfr[j] = *(const bf16x8*)(&Bs[cur][n*32 + ((quad ^ ((n >> 1) & 3))*8)]);
        }
        #pragma unroll
        for (int i = 0; i < 4; i++)
            #pragma unroll
            for (int j = 0; j < 4; j++)
                acc[i][j] = MFMA16(af[i], bfr[j], acc[i][j]);
        if (ki + 1 < nk){
            if (AFP32){
                *(bf16x8*)&As[nxt][la0] = norm_pack(xa0l, xa0h, pwl, pwh, pbl, pbh, nmu0, rr0);
                *(bf16x8*)&As[nxt][la1] = norm_pack(xa1l, xa1h, pwl, pwh, pbl, pbh, nmu1, rr1);
            } else {
                *(bf16x8*)&As[nxt][la0] = pa0; *(bf16x8*)&As[nxt][la1] = pa1;
            }
            *(bf16x8*)&Bs[nxt][la0] = pb0; *(bf16x8*)&Bs[nxt][la1] = pb1;
        }
        __syncthreads();
    }

    #pragma unroll
    for (int i = 0; i < 4; i++){
        #pragma unroll
        for (int j = 0; j < 4; j++){
            #pragma unroll
            for (int r = 0; r < 4; r++){
                size_t row = (size_t)(m_base + mrow0 + 16*i + quad*4 + r);
                int    col = n_base + ncol0 + 16*j + l15;
                float v = acc[i][j][r] + bias[col];
                if (EPI == 1) v = gelu_f(v);
                if (RES == 2) v += ((const float*)resp)[row*N + col];
                if (SPLITV){
                    if (col < 1536) ((short*)Cp )[row*1536 + col]        = f2bs(v);
                    else            ((short*)Cp2)[row*768  + col - 1536] = f2bs(v);
                } else if (OUT == 0) ((short*)Cp)[row*N + col] = f2bs(v);
                else                 ((float*)Cp)[row*N + col] = v;
            }
        }
    }
}

// ---------------- thin MFMA GEMM: 128x64 tile, BK=32, reg dbuf, XCD swizzle ------------
template<int EPI, int RES, int OUT>
__global__ __launch_bounds__(256) void gemm_bt_thin(const short* __restrict__ A,
                                                    const short* __restrict__ Bt,
                                                    const float* __restrict__ bias,
                                                    const void* __restrict__ resp,
                                                    void* __restrict__ Cp,
                                                    int N, int K, int NXB)
{
    __shared__ alignas(16) short As[2][128*32];
    __shared__ alignas(16) short Bs[2][64*32];
    int tid = threadIdx.x, lane = tid & 63, w = tid >> 6;
    int l15 = lane & 15, quad = lane >> 4;
    int bx, by; xcd_map(NXB, bx, by);
    int m_base = by*128, n_base = bx*64;

    int r4 = lane >> 2;
    int sG = ((lane & 3) ^ ((r4 >> 1) & 3)) * 8;
    const short* gA0 = A  + (size_t)(m_base + 32*w      + r4)*K + sG;
    const short* gA1 = A  + (size_t)(m_base + 32*w + 16 + r4)*K + sG;
    const short* gB0 = Bt + (size_t)(n_base + 16*w      + r4)*K + sG;
    int la0 = (2*w)*512 + lane*8, la1 = (2*w+1)*512 + lane*8;
    int lb0 = w*512 + lane*8;

    f32x4 acc[2][4] = {};

    bf16x8 pa0 = *(const bf16x8*)gA0, pa1 = *(const bf16x8*)gA1;
    bf16x8 pb0 = *(const bf16x8*)gB0;
    *(bf16x8*)&As[0][la0] = pa0; *(bf16x8*)&As[0][la1] = pa1;
    *(bf16x8*)&Bs[0][lb0] = pb0;
    __syncthreads();

    int nk = K >> 5;
    for (int ki = 0; ki < nk; ki++){
        int cur = ki & 1, nxt = cur ^ 1;
        if (ki + 1 < nk){
            int off = (ki + 1) << 5;
            pa0 = *(const bf16x8*)(gA0 + off); pa1 = *(const bf16x8*)(gA1 + off);
            pb0 = *(const bf16x8*)(gB0 + off);
        }
        bf16x8 af[2], bfr[4];
        #pragma unroll
        for (int i = 0; i < 2; i++){
            int m = 32*w + 16*i + l15;
            af[i] = *(const bf16x8*)(&As[cur][m*32 + ((quad ^ ((m >> 1) & 3))*8)]);
        }
        #pragma unroll
        for (int j = 0; j < 4; j++){
            int n = 16*j + l15;
            bfr[j] = *(const bf16x8*)(&Bs[cur][n*32 + ((quad ^ ((n >> 1) & 3))*8)]);
        }
        #pragma unroll
        for (int i = 0; i < 2; i++)
            #pragma unroll
            for (int j = 0; j < 4; j++)
                acc[i][j] = MFMA16(af[i], bfr[j], acc[i][j]);
        if (ki + 1 < nk){
            *(bf16x8*)&As[nxt][la0] = pa0; *(bf16x8*)&As[nxt][la1] = pa1;
            *(bf16x8*)&Bs[nxt][lb0] = pb0;
        }
        __syncthreads();
    }

    #pragma unroll
    for (int i = 0; i < 2; i++){
        #pragma unroll
        for (int j = 0; j < 4; j++){
            #pragma unroll
            for (int r = 0; r < 4; r++){
                size_t row = (size_t)(m_base + 32*w + 16*i + quad*4 + r);
                int    col = n_base + 16*j + l15;
                float v = acc[i][j][r] + bias[col];
                if (EPI == 1) v = gelu_f(v);
                if (RES == 2) v += ((const float*)resp)[row*N + col];
                if (OUT == 0) ((short*)Cp)[row*N + col] = f2bs(v);
                else          ((float*)Cp)[row*N + col] = v;
            }
        }
    }
}

// ---------------- MFMA flash attention: reg-staged K/V dbuf, XCD-owns-heads ------------
// 1D grid 768: xcd = bid&7 owns 12 (b,h) heads entirely -> K/V stay in its L2.
__global__ __launch_bounds__(256) void flash_attn(const short* __restrict__ qk,
                                                  const short* __restrict__ vT,
                                                  short* __restrict__ z)
{
    __shared__ alignas(16) short U[4608];        // Q tile [64][64] swz / Ps [4][16][72]
    __shared__ alignas(16) short Ks[2][64*64];
    __shared__ alignas(16) short Vt[2][64*64];
    int bid = blockIdx.x;
    int xcd = bid & 7, slot = bid >> 3;
    int hb = xcd*12 + (slot >> 3);   // 0..95
    int p  = slot & 7;
    int b = hb / NH, h = hb % NH;
    int tid = threadIdx.x, lane = tid & 63, w = tid >> 6;
    int l15 = lane & 15, quad = lane >> 4;
    int r8 = lane >> 3, u8 = lane & 7;
    int useg = (u8 ^ r8) * 8;
    int lc0 = (2*w)*512 + lane*8, lc1 = (2*w+1)*512 + lane*8;

    const short* kbase = qk + DM + h*DH;
    const short* vbase = vT + (size_t)(b*NH + h)*DH*SEQ;

    for (int phase = 0; phase < 2; phase++){
        int qt = phase ? (15 - p) : p;

        __syncthreads();
        {
            bf16x8 q0 = *(const bf16x8*)(qk + (size_t)(b*SEQ + qt*64 + 16*w + r8)*1536 + h*DH + useg);
            bf16x8 q1 = *(const bf16x8*)(qk + (size_t)(b*SEQ + qt*64 + 16*w + 8 + r8)*1536 + h*DH + useg);
            bf16x8 k0 = *(const bf16x8*)(kbase + (size_t)(b*SEQ + 16*w + r8)*1536 + useg);
            bf16x8 k1 = *(const bf16x8*)(kbase + (size_t)(b*SEQ + 16*w + 8 + r8)*1536 + useg);
            bf16x8 v0 = *(const bf16x8*)(vbase + (size_t)(16*w + r8)*SEQ + useg);
            bf16x8 v1 = *(const bf16x8*)(vbase + (size_t)(16*w + 8 + r8)*SEQ + useg);
            *(bf16x8*)&U[lc0] = q0;        *(bf16x8*)&U[lc1] = q1;
            *(bf16x8*)&Ks[0][lc0] = k0;    *(bf16x8*)&Ks[0][lc1] = k1;
            *(bf16x8*)&Vt[0][lc0] = v0;    *(bf16x8*)&Vt[0][lc1] = v1;
        }
        __syncthreads();

        bf16x8 aq[2];
        #pragma unroll
        for (int kk = 0; kk < 2; kk++)
            aq[kk] = *(const bf16x8*)(U + (16*w + l15)*64 + (((4*kk + quad) ^ (l15 & 7))*8));

        float m_state[4] = {-1e30f,-1e30f,-1e30f,-1e30f};
        float l_state[4] = {0.f,0.f,0.f,0.f};
        f32x4 o_acc[4] = {};
        int rg = qt*64 + w*16 + quad*4;

        for (int kt = 0; kt <= qt; ++kt){
            int cur = kt & 1, nxt = cur ^ 1;
            bf16x8 pk0, pk1, pv0, pv1;
            if (kt < qt){
                pk0 = *(const bf16x8*)(kbase + (size_t)(b*SEQ + (kt+1)*64 + 16*w + r8)*1536 + useg);
                pk1 = *(const bf16x8*)(kbase + (size_t)(b*SEQ + (kt+1)*64 + 16*w + 8 + r8)*1536 + useg);
                pv0 = *(const bf16x8*)(vbase + (size_t)(16*w + r8)*SEQ + (kt+1)*64 + useg);
                pv1 = *(const bf16x8*)(vbase + (size_t)(16*w + 8 + r8)*SEQ + (kt+1)*64 + useg);
            }

            f32x4 s[4] = {};
            #pragma unroll
            for (int kk = 0; kk < 2; kk++){
                int swz = ((4*kk + quad) ^ (l15 & 7)) * 8;
                #pragma unroll
                for (int j = 0; j < 4; j++){
                    bf16x8 bk = *(const bf16x8*)(&Ks[cur][(16*j + l15)*64 + swz]);
                    s[j] = MFMA16(aq[kk], bk, s[j]);
                }
            }

            bool diag = (kt == qt);
            #pragma unroll
            for (int j = 0; j < 4; j++){
                int col_g = kt*64 + 16*j + l15;
                #pragma unroll
                for (int r = 0; r < 4; r++){
                    float v = s[j][r] * 0.125f;
                    if (diag && col_g > rg + r) v = -1e30f;
                    s[j][r] = v;
                }
            }

            #pragma unroll
            for (int r = 0; r < 4; r++){
                float mx = fmaxf(fmaxf(s[0][r], s[1][r]), fmaxf(s[2][r], s[3][r]));
                #pragma unroll
                for (int d = 1; d < 16; d <<= 1) mx = fmaxf(mx, __shfl_xor(mx, d, 64));
                float m_new = fmaxf(m_state[r], mx);
                float alpha = __expf(m_state[r] - m_new);
                m_state[r] = m_new;
                float rs = 0.f;
                #pragma unroll
                for (int j = 0; j < 4; j++){
                    float pv = __expf(s[j][r] - m_new);
                    s[j][r] = pv; rs += pv;
                }
                #pragma unroll
                for (int d = 1; d < 16; d <<= 1) rs += __shfl_xor(rs, d, 64);
                l_state[r] = l_state[r]*alpha + rs;
                #pragma unroll
                for (int j = 0; j < 4; j++) o_acc[j][r] *= alpha;
            }

            #pragma unroll
            for (int j = 0; j < 4; j++)
                #pragma unroll
                for (int r = 0; r < 4; r++)
                    U[w*1152 + (quad*4 + r)*72 + 16*j + l15] = f2bs(s[j][r]);

            #pragma unroll
            for (int kk = 0; kk < 2; kk++){
                bf16x8 ap = *(const bf16x8*)(U + w*1152 + l15*72 + 32*kk + quad*8);
                int swz = ((4*kk + quad) ^ (l15 & 7)) * 8;
                #pragma unroll
                for (int j = 0; j < 4; j++){
                    bf16x8 bv = *(const bf16x8*)(&Vt[cur][(16*j + l15)*64 + swz]);
                    o_acc[j] = MFMA16(ap, bv, o_acc[j]);
                }
            }

            if (kt < qt){
                *(bf16x8*)&Ks[nxt][lc0] = pk0;  *(bf16x8*)&Ks[nxt][lc1] = pk1;
                *(bf16x8*)&Vt[nxt][lc0] = pv0;  *(bf16x8*)&Vt[nxt][lc1] = pv1;
            }
            __syncthreads();
        }

        #pragma unroll
        for (int r = 0; r < 4; r++){
            float inv_l = 1.0f / l_state[r];
            size_t row = (size_t)(b*SEQ + rg + r);
            #pragma unroll
            for (int j = 0; j < 4; j++)
                z[row*DM + h*DH + 16*j + l15] = f2bs(o_acc[j][r] * inv_l);
        }
    }
}

// ---------------- launch ----------------
// ws map (59,909,120 B, lifetime-aliased; fused-LN dataflow):
//   A0 [0, 3538944)          wqkvT  -> WinT (A0+A1) after O-gemm
//   A1 [3538944, 4718592)    WOT
//   A2 [4718592, 4727808)    bias_qkv fp32
//   A3 [4727808, 29893632)   qk bf16 [qkv-gemm -> flash]  }
//   A4 [29893632, 42476544)  v_rm -> zbuf [flash -> O]    } hidden bf16 50,331,648 B
//   A5 [42476544, 55059456)  vT [transpose_v -> flash]    }   [MLP-in -> MLP-out]
//   A6 [55059456, 59778048)  WoutT
//   stats1 @ 59778048 (64KB), stats2 @ 59843584 (64KB)
// resid_mid lives in d_out (fp32): O-gemm writes it, MLP reads it via fused LN + residual.
extern "C" void kernel_launch(void* const* d_in, const int* in_sizes, int n_in,
                              void* d_out, int out_size, void* d_ws, size_t ws_size,
                              hipStream_t stream)
{
    const float* resid_pre = (const float*)d_in[0];
    const float* W_Q  = (const float*)d_in[1];
    const float* W_K  = (const float*)d_in[2];
    const float* W_V  = (const float*)d_in[3];
    const float* W_O  = (const float*)d_in[4];
    const float* b_Q  = (const float*)d_in[5];
    const float* b_K  = (const float*)d_in[6];
    const float* b_V  = (const float*)d_in[7];
    const float* b_O  = (const float*)d_in[8];
    const float* ln1w = (const float*)d_in[9];
    const float* ln1b = (const float*)d_in[10];
    const float* ln2w = (const float*)d_in[11];
    const float* ln2b = (const float*)d_in[12];
    const float* W_in = (const float*)d_in[13];
    const float* b_in = (const float*)d_in[14];
    const float* W_out= (const float*)d_in[15];
    const float* b_out= (const float*)d_in[16];

    char* ws = (char*)d_ws;
    short*  wqkvT    = (short*)(ws);
    short*  WOT      = (short*)(ws + 3538944);
    float*  bias_qkv = (float*)(ws + 4718592);
    short*  WinT     = (short*)(ws);             // after O-gemm
    short*  qk       = (short*)(ws + 4727808);   // A3
    short*  hidden   = (short*)(ws + 4727808);   // A3+A4+A5 after flash/O-gemm
    short*  v_rm     = (short*)(ws + 29893632);  // A4
    short*  zbuf     = (short*)(ws + 29893632);  // A4 after transpose_v
    short*  vT       = (short*)(ws + 42476544);  // A5
    short*  WoutT    = (short*)(ws + 55059456);  // A6
    float2* stats1   = (float2*)(ws + 59778048);
    float2* stats2   = (float2*)(ws + 59843584);

    // prep
    transpose_cvt_qkv<<<dim3(2, 24, 36), dim3(256), 0, stream>>>(W_Q, W_K, W_V, wqkvT);
    prep_qkv_bias<<<dim3(9), dim3(256), 0, stream>>>(b_Q, b_K, b_V, bias_qkv);
    transpose_cvt<<<dim3(24, 24), dim3(256), 0, stream>>>(W_O,   WOT,   DM,   DM);
    transpose_cvt<<<dim3(24, 96), dim3(256), 0, stream>>>(W_out, WoutT, DMLP, DM);

    // ln1 stats + QKV projection w/ fused LN (split: Q,K -> qk, V -> v_rm)
    ln_stats<<<dim3(NTOK), dim3(256), 0, stream>>>(resid_pre, stats1);
    gemm_bt<0,0,0,1,1><<<dim3(18*64), dim3(256), 0, stream>>>(
        resid_pre, wqkvT, bias_qkv, nullptr, stats1, ln1w, ln1b, qk, v_rm, QKVN, DM, 18);

    // V transpose then flash attention (XCD-owns-heads swizzle)
    transpose_v<<<dim3(SEQ/64, NH, BATCH), dim3(256), 0, stream>>>(v_rm, vT);
    flash_attn<<<dim3(768), dim3(256), 0, stream>>>(qk, vT, zbuf);

    // O projection + residual(resid_pre fp32) -> d_out fp32
    gemm_bt_thin<0,2,1><<<dim3(12*64), dim3(256), 0, stream>>>(
        zbuf, WOT, b_O, resid_pre, d_out, DM, DM, 12);

    // W_in transpose (A0/A1 dead)
    transpose_cvt<<<dim3(96, 24), dim3(256), 0, stream>>>(W_in, WinT, DM, DMLP);

    // ln2 stats on d_out (fp32)
    ln_stats<<<dim3(NTOK), dim3(256), 0, stream>>>((const float*)d_out, stats2);

    // MLP single-pass: in (fused LN + gelu) -> hidden; out (+residual, in-place d_out)
    gemm_bt<1,0,0,0,1><<<dim3(24*64), dim3(256), 0, stream>>>(
        d_out, WinT, b_in, nullptr, stats2, ln2w, ln2b, hidden, nullptr, DMLP, DM, 24);
    gemm_bt_thin<0,2,1><<<dim3(12*64), dim3(256), 0, stream>>>(
        hidden, WoutT, b_out, d_out, d_out, DM, DMLP, 12);
}